// Round 6
// baseline (185.281 us; speedup 1.0000x reference)
//
#include <hip/hip_runtime.h>

// B=2, C=256, X=Y=Z=16 -> N=4096, GROUPS=8, HEADS=8, D=32
#define NB 2
#define NC 256
#define NT 4096
#define NG 8
#define NH 8
#define EPSV 1e-5f
// (1/sqrt(32)) * log2(e): folded into Q at projection time -> softmax is exp2()
#define SCALE_L2E 0.25503164427f
#define NCHUNK 4
#define CHTOK (NT / NCHUNK)                 // 1024 tokens per chunk
#define PO_ELEMS ((size_t)NB * NC * NT)     // bf16 elements per chunk of partial O

typedef __attribute__((ext_vector_type(8))) __bf16 bf16x8;
typedef __attribute__((ext_vector_type(8))) unsigned short u16x8;
typedef __attribute__((ext_vector_type(4))) unsigned short u16x4;
typedef __attribute__((ext_vector_type(4))) unsigned int u32x4;
typedef __attribute__((ext_vector_type(4))) float f32x4;

static __device__ __forceinline__ unsigned short f2bf(float f) {
    union { float f; unsigned int u; } v; v.f = f;
    unsigned int r = v.u + 0x7fffu + ((v.u >> 16) & 1u);  // RNE
    return (unsigned short)(r >> 16);
}
static __device__ __forceinline__ float bf2f(unsigned short u) {
    union { unsigned int u; float f; } v; v.u = ((unsigned int)u) << 16;
    return v.f;
}
static __device__ __forceinline__ bf16x8 ldbf8(const unsigned short* p) {
    u16x8 u = *(const u16x8*)p;
    return __builtin_bit_cast(bf16x8, u);
}
static __device__ __forceinline__ unsigned int cvtpk(float lo, float hi) {
    unsigned int d;
    asm("v_cvt_pk_bf16_f32 %0, %1, %2" : "=v"(d) : "v"(lo), "v"(hi));
    return d;
}

// ---------------- GroupNorm statistics (two-stage, deterministic) ------------
__global__ __launch_bounds__(256) void k_stats_partial(const float* __restrict__ x,
                                                       float* __restrict__ part) {
    int bg = blockIdx.x >> 5;
    int p  = blockIdx.x & 31;
    const float4* base = (const float4*)(x + (size_t)bg * 131072 + (size_t)p * 4096);
    float s = 0.f, s2 = 0.f;
#pragma unroll
    for (int i = 0; i < 4; ++i) {
        float4 v = base[threadIdx.x + i * 256];
        s  += v.x + v.y + v.z + v.w;
        s2 += v.x * v.x + v.y * v.y + v.z * v.z + v.w * v.w;
    }
    __shared__ float ss[256], sq[256];
    ss[threadIdx.x] = s; sq[threadIdx.x] = s2;
    __syncthreads();
    for (int off = 128; off > 0; off >>= 1) {
        if (threadIdx.x < off) {
            ss[threadIdx.x] += ss[threadIdx.x + off];
            sq[threadIdx.x] += sq[threadIdx.x + off];
        }
        __syncthreads();
    }
    if (threadIdx.x == 0) {
        part[blockIdx.x * 2 + 0] = ss[0];
        part[blockIdx.x * 2 + 1] = sq[0];
    }
}

__global__ __launch_bounds__(64) void k_stats_final(const float* __restrict__ part,
                                                    float* __restrict__ stats) {
    int bg = blockIdx.x;
    float s = 0.f, s2 = 0.f;
    if (threadIdx.x < 32) {
        s  = part[(bg * 32 + threadIdx.x) * 2 + 0];
        s2 = part[(bg * 32 + threadIdx.x) * 2 + 1];
    }
#pragma unroll
    for (int off = 16; off > 0; off >>= 1) {
        s  += __shfl_down(s, off);
        s2 += __shfl_down(s2, off);
    }
    if (threadIdx.x == 0) {
        const float inv = 1.0f / 131072.0f;
        float mean = s * inv;
        float var  = s2 * inv - mean * mean;
        stats[bg * 2 + 0] = mean;
        stats[bg * 2 + 1] = rsqrtf(var + EPSV);
    }
}

// ---------------- QKV projection GEMM (fp32 core, bf16 transposed epilogue) --
__global__ __launch_bounds__(256) void k_qkv(const float* __restrict__ x,
                                             const float* __restrict__ wqkv,
                                             const float* __restrict__ nw,
                                             const float* __restrict__ nbias,
                                             const float* __restrict__ stats,
                                             unsigned short* __restrict__ qkT,
                                             unsigned short* __restrict__ vbf) {
    __shared__ float As[32][68];
    __shared__ float Bs[32][68];
    int b = blockIdx.z, o0 = blockIdx.y * 64, n0 = blockIdx.x * 64;
    int tid = threadIdx.x, tx = tid & 15, ty = tid >> 4;
    float acc[4][4] = {};
    for (int c0 = 0; c0 < NC; c0 += 32) {
        int g = c0 >> 5;
        float mean = stats[(b * NG + g) * 2 + 0];
        float rstd = stats[(b * NG + g) * 2 + 1];
#pragma unroll
        for (int r = 0; r < 8; ++r) {
            int idx = r * 256 + tid;
            int ol = idx >> 5, cl = idx & 31;
            As[cl][ol] = wqkv[(size_t)(o0 + ol) * NC + c0 + cl];
        }
#pragma unroll
        for (int r = 0; r < 8; ++r) {
            int idx = r * 256 + tid;
            int cl = idx >> 6, nl = idx & 63;
            int c = c0 + cl;
            float v = x[((size_t)(b * NC + c)) * NT + n0 + nl];
            Bs[cl][nl] = (v - mean) * rstd * nw[c] + nbias[c];
        }
        __syncthreads();
#pragma unroll
        for (int k = 0; k < 32; ++k) {
            float4 a = *(const float4*)&As[k][ty * 4];
            float4 bv = *(const float4*)&Bs[k][tx * 4];
            float av[4] = {a.x, a.y, a.z, a.w};
            float bw[4] = {bv.x, bv.y, bv.z, bv.w};
#pragma unroll
            for (int i = 0; i < 4; ++i)
#pragma unroll
                for (int j = 0; j < 4; ++j)
                    acc[i][j] += av[i] * bw[j];
        }
        __syncthreads();
    }
    if (blockIdx.y < 8) {
        int o = o0 + ty * 4;
        int qk = o >> 8;
        int hh = (o >> 5) & 7;
        int d4 = o & 31;
        float sc = (qk == 0) ? SCALE_L2E : 1.0f;
        unsigned short* dst = qkT + ((((size_t)qk * NB + b) * NH + hh) * NT) * 32;
#pragma unroll
        for (int j = 0; j < 4; ++j) {
            int tok = n0 + tx * 4 + j;
            u16x4 pk = { f2bf(acc[0][j] * sc), f2bf(acc[1][j] * sc),
                         f2bf(acc[2][j] * sc), f2bf(acc[3][j] * sc) };
            *(u16x4*)&dst[(size_t)tok * 32 + d4] = pk;
        }
    } else {
        int o = o0 + ty * 4;
        int hh = (o >> 5) & 7;
        int d = o & 31;
        unsigned short* dst = vbf + (((size_t)b * NH + hh) * 32) * NT;
#pragma unroll
        for (int i = 0; i < 4; ++i) {
            u16x4 pk = { f2bf(acc[i][0]), f2bf(acc[i][1]),
                         f2bf(acc[i][2]), f2bf(acc[i][3]) };
            *(u16x4*)&dst[(size_t)(d + i) * NT + n0 + tx * 4] = pk;
        }
    }
}

// ---------------- Attention: swapped-QK^T bf16 MFMA, split-token, no LDS -----
// grid (32, NH, NB*NCHUNK), 256 threads = 4 waves; wave owns 32 queries,
// sweeps its 1024-token chunk. P redistribution (C/D rows g*4+r -> B-frag
// k rows g*8+j) done in-register: 2x permlane32_swap + 2x ds_swizzle(xor16).
__global__ __launch_bounds__(256, 8) void k_attn(const unsigned short* __restrict__ qkT,
                                                 const unsigned short* __restrict__ vbf,
                                                 unsigned short* __restrict__ pO,
                                                 float* __restrict__ pl) {
    int sb = blockIdx.x, h = blockIdx.y;
    int b  = blockIdx.z >> 2, ch = blockIdx.z & 3;
    int tid = threadIdx.x;
    int w = tid >> 6, lane = tid & 63, col = lane & 15, g = lane >> 4;
    bool b4 = (g & 1) != 0;
    int s0 = sb * 128 + w * 32;

    const unsigned short* qB = qkT + ((((size_t)0 * NB + b) * NH + h) * NT) * 32;
    const unsigned short* kB = qkT + ((((size_t)1 * NB + b) * NH + h) * NT) * 32;
    const unsigned short* vB = vbf + (((size_t)b * NH + h) * 32) * NT;

    // Q fragments (B-operand): col = s, k = d = g*8+j. Scale pre-folded.
    bf16x8 qf[2];
    qf[0] = ldbf8(qB + (size_t)(s0 + col) * 32 + g * 8);
    qf[1] = ldbf8(qB + (size_t)(s0 + 16 + col) * 32 + g * 8);

    u16x8 ou;
#pragma unroll
    for (int j = 0; j < 8; ++j) ou[j] = 0x3F80;  // bf16 1.0
    const bf16x8 ones = __builtin_bit_cast(bf16x8, ou);

    f32x4 oacc[2][2] = {};     // [d-tile][s-tile]
    f32x4 lacc[2] = {};        // [s-tile] partial softmax denominator

    const unsigned short* kA0 = kB + ((size_t)(ch * CHTOK) + col) * 32 + g * 8;
    const unsigned short* vA0 = vB + (size_t)col * NT + ch * CHTOK + g * 8;
    const unsigned short* vA1 = vB + (size_t)(16 + col) * NT + ch * CHTOK + g * 8;

    for (int it = 0; it < CHTOK / 32; ++it) {
        bf16x8 k0 = ldbf8(kA0 + it * 1024);
        bf16x8 k1 = ldbf8(kA0 + it * 1024 + 512);
        bf16x8 v0 = ldbf8(vA0 + it * 32);
        bf16x8 v1 = ldbf8(vA1 + it * 32);
        const f32x4 z = {0.f, 0.f, 0.f, 0.f};
#pragma unroll
        for (int st = 0; st < 2; ++st) {
            // S^T tiles: rows t (tt=0: k0, tt=1: k1), col s. Lane: rows g*4+r.
            f32x4 sa = __builtin_amdgcn_mfma_f32_16x16x32_bf16(k0, qf[st], z, 0, 0, 0);
            f32x4 sb2 = __builtin_amdgcn_mfma_f32_16x16x32_bf16(k1, qf[st], z, 0, 0, 0);
            // no-max softmax (logits bounded): P = exp2(S)
            unsigned int W0 = cvtpk(__builtin_amdgcn_exp2f(sa[0]),
                                    __builtin_amdgcn_exp2f(sa[1]));   // unit g*2
            unsigned int W1 = cvtpk(__builtin_amdgcn_exp2f(sa[2]),
                                    __builtin_amdgcn_exp2f(sa[3]));   // unit g*2+1
            unsigned int W2 = cvtpk(__builtin_amdgcn_exp2f(sb2[0]),
                                    __builtin_amdgcn_exp2f(sb2[1]));  // unit 8+g*2
            unsigned int W3 = cvtpk(__builtin_amdgcn_exp2f(sb2[2]),
                                    __builtin_amdgcn_exp2f(sb2[3]));  // unit 8+g*2+1
            // stage A: swap across lane bit5. o0={W0.lo,W2.lo}, o1={W0.hi,W2.hi}
            unsigned int o0 = W0, o1 = W2;
            asm("v_permlane32_swap_b32 %0, %1" : "+v"(o0), "+v"(o1));
            unsigned int e0 = W1, e1 = W3;
            asm("v_permlane32_swap_b32 %0, %1" : "+v"(e0), "+v"(e1));
            // stage B: exchange with bit4 neighbor (send o1/e1 if b4==0 else o0/e0)
            unsigned int vo = b4 ? o0 : o1;
            unsigned int ve = b4 ? e0 : e1;
            unsigned int svo = (unsigned int)__builtin_amdgcn_ds_swizzle((int)vo, 0x401F);
            unsigned int sve = (unsigned int)__builtin_amdgcn_ds_swizzle((int)ve, 0x401F);
            // B-fragment words j=0..3 = units 4g+j (t rows g*8 .. g*8+7)
            u32x4 pbw = { b4 ? svo : o0, b4 ? sve : e0,
                          b4 ? o1 : svo, b4 ? e1 : sve };
            bf16x8 pf = __builtin_bit_cast(bf16x8, pbw);
            lacc[st]    = __builtin_amdgcn_mfma_f32_16x16x32_bf16(ones, pf, lacc[st], 0, 0, 0);
            oacc[0][st] = __builtin_amdgcn_mfma_f32_16x16x32_bf16(v0, pf, oacc[0][st], 0, 0, 0);
            oacc[1][st] = __builtin_amdgcn_mfma_f32_16x16x32_bf16(v1, pf, oacc[1][st], 0, 0, 0);
        }
    }

    unsigned short* pOc = pO + (size_t)ch * PO_ELEMS;
#pragma unroll
    for (int dt = 0; dt < 2; ++dt)
#pragma unroll
        for (int st = 0; st < 2; ++st) {
            int s = s0 + st * 16 + col;
            unsigned int u0 = cvtpk(oacc[dt][st][0], oacc[dt][st][1]);
            unsigned int u1 = cvtpk(oacc[dt][st][2], oacc[dt][st][3]);
            size_t base = ((size_t)(b * NC + h * 32 + dt * 16 + g * 4)) * NT + s;
            pOc[base]          = (unsigned short)(u0 & 0xFFFF);
            pOc[base + NT]     = (unsigned short)(u0 >> 16);
            pOc[base + 2 * NT] = (unsigned short)(u1 & 0xFFFF);
            pOc[base + 3 * NT] = (unsigned short)(u1 >> 16);
        }
    if (g == 0) {
#pragma unroll
        for (int st = 0; st < 2; ++st) {
            int s = s0 + st * 16 + col;
            pl[(((size_t)ch * NB + b) * NH + h) * NT + s] = lacc[st][0];
        }
    }
}

// ---------------- Combine partial chunks: att = sum(O) / sum(l) (bf16) -------
__global__ __launch_bounds__(256) void k_combine(const unsigned short* __restrict__ pO,
                                                 const float* __restrict__ pl,
                                                 unsigned short* __restrict__ att) {
    int f = blockIdx.x * 256 + threadIdx.x;   // quad index, 524288 total
    int b  = f >> 18;
    int r  = f & 262143;
    int c  = r >> 10;
    int sq = (r & 1023) * 4;
    int h  = c >> 5;
    float num[4] = {0.f, 0.f, 0.f, 0.f};
    float den[4] = {0.f, 0.f, 0.f, 0.f};
#pragma unroll
    for (int chn = 0; chn < NCHUNK; ++chn) {
        u16x4 ov = *(const u16x4*)&pO[(size_t)chn * PO_ELEMS + (size_t)f * 4];
        float4 lv = *(const float4*)&pl[(((size_t)chn * NB + b) * NH + h) * NT + sq];
        num[0] += bf2f(ov[0]); num[1] += bf2f(ov[1]);
        num[2] += bf2f(ov[2]); num[3] += bf2f(ov[3]);
        den[0] += lv.x; den[1] += lv.y; den[2] += lv.z; den[3] += lv.w;
    }
    u16x4 res = { f2bf(num[0] / den[0]), f2bf(num[1] / den[1]),
                  f2bf(num[2] / den[2]), f2bf(num[3] / den[3]) };
    *(u16x4*)&att[(size_t)f * 4] = res;
}

// ---------------- Output projection GEMM + bias + residual (bf16 att in) -----
__global__ __launch_bounds__(256) void k_out(const unsigned short* __restrict__ att,
                                             const float* __restrict__ wout,
                                             const float* __restrict__ bout,
                                             const float* __restrict__ x,
                                             float* __restrict__ out) {
    __shared__ float As[32][68];
    __shared__ float Bs[32][68];
    int b = blockIdx.z, o0 = blockIdx.y * 64, n0 = blockIdx.x * 64;
    int tid = threadIdx.x, tx = tid & 15, ty = tid >> 4;
    float acc[4][4] = {};
    for (int c0 = 0; c0 < NC; c0 += 32) {
#pragma unroll
        for (int r = 0; r < 8; ++r) {
            int idx = r * 256 + tid;
            int ol = idx >> 5, cl = idx & 31;
            As[cl][ol] = wout[(size_t)(o0 + ol) * NC + c0 + cl];
        }
#pragma unroll
        for (int r = 0; r < 2; ++r) {
            int q = r * 256 + tid;
            int cl = q >> 4, nq = (q & 15) * 4;
            u16x4 v4 = *(const u16x4*)&att[((size_t)(b * NC + c0 + cl)) * NT + n0 + nq];
            Bs[cl][nq + 0] = bf2f(v4[0]);
            Bs[cl][nq + 1] = bf2f(v4[1]);
            Bs[cl][nq + 2] = bf2f(v4[2]);
            Bs[cl][nq + 3] = bf2f(v4[3]);
        }
        __syncthreads();
#pragma unroll
        for (int k = 0; k < 32; ++k) {
            float4 a = *(const float4*)&As[k][ty * 4];
            float4 bv = *(const float4*)&Bs[k][tx * 4];
            float av[4] = {a.x, a.y, a.z, a.w};
            float bw[4] = {bv.x, bv.y, bv.z, bv.w};
#pragma unroll
            for (int i = 0; i < 4; ++i)
#pragma unroll
                for (int j = 0; j < 4; ++j)
                    acc[i][j] += av[i] * bw[j];
        }
        __syncthreads();
    }
#pragma unroll
    for (int i = 0; i < 4; ++i) {
        int o = o0 + ty * 4 + i;
        float bo = bout[o];
        size_t rowoff = ((size_t)(b * NC + o)) * NT + n0 + tx * 4;
        float4 xr = *(const float4*)&x[rowoff];
        float4 st = {acc[i][0] + bo + xr.x, acc[i][1] + bo + xr.y,
                     acc[i][2] + bo + xr.z, acc[i][3] + bo + xr.w};
        *(float4*)&out[rowoff] = st;
    }
}

extern "C" void kernel_launch(void* const* d_in, const int* in_sizes, int n_in,
                              void* d_out, int out_size, void* d_ws, size_t ws_size,
                              hipStream_t stream) {
    const float* x    = (const float*)d_in[0];
    const float* nw   = (const float*)d_in[1];
    const float* nb   = (const float*)d_in[2];
    const float* wqkv = (const float*)d_in[3];
    const float* wout = (const float*)d_in[4];
    const float* bout = (const float*)d_in[5];
    float* out = (float*)d_out;
    char* wsb = (char*)d_ws;

    unsigned short* qkT = (unsigned short*)wsb;                        // 8 MB: [2][B][H][4096][32] bf16
    unsigned short* vbf = (unsigned short*)(wsb + 8u * 1024 * 1024);   // 4 MB: [B][H][32][4096] bf16
    unsigned short* pO  = (unsigned short*)(wsb + 12u * 1024 * 1024);  // 16 MB: [4ch][B][C][N] bf16
    float* pl   = (float*)(wsb + 28u * 1024 * 1024);                   // 1 MB: [4ch][B][H][N] f32
    float* part = (float*)(wsb + 29u * 1024 * 1024);
    float* stats = part + 1024;
    // att (bf16, 4 MB) aliases the dead qkT region: k_attn finished reading
    // qkT before k_combine writes it; k_qkv rewrites qkT fully every call.
    unsigned short* att = qkT;

    k_stats_partial<<<512, 256, 0, stream>>>(x, part);
    k_stats_final<<<16, 64, 0, stream>>>(part, stats);
    k_qkv<<<dim3(NT / 64, 768 / 64, NB), 256, 0, stream>>>(x, wqkv, nw, nb, stats, qkT, vbf);
    k_attn<<<dim3(32, NH, NB * NCHUNK), 256, 0, stream>>>(qkT, vbf, pO, pl);
    k_combine<<<2048, 256, 0, stream>>>(pO, pl, att);
    k_out<<<dim3(NT / 64, NC / 64, NB), 256, 0, stream>>>(att, wout, bout, x, out);
}

// Round 8
// 160.405 us; speedup vs baseline: 1.1551x; 1.1551x over previous
//
#include <hip/hip_runtime.h>

// B=2, C=256, X=Y=Z=16 -> N=4096, GROUPS=8, HEADS=8, D=32
#define NB 2
#define NC 256
#define NT 4096
#define NG 8
#define NH 8
#define EPSV 1e-5f
// (1/sqrt(32)) * log2(e): folded into Q at projection time -> softmax is exp2()
#define SCALE_L2E 0.25503164427f
#define NCHUNK 4
#define CHTOK (NT / NCHUNK)                 // 1024 tokens per chunk
#define NIT (CHTOK / 32)                    // 32 iterations per chunk
#define PO_ELEMS ((size_t)NB * NC * NT)     // bf16 elements per chunk of partial O

typedef __attribute__((ext_vector_type(8))) __bf16 bf16x8;
typedef __attribute__((ext_vector_type(8))) unsigned short u16x8;
typedef __attribute__((ext_vector_type(4))) unsigned short u16x4;
typedef __attribute__((ext_vector_type(4))) unsigned int u32x4;
typedef __attribute__((ext_vector_type(4))) float f32x4;

static __device__ __forceinline__ unsigned short f2bf(float f) {
    union { float f; unsigned int u; } v; v.f = f;
    unsigned int r = v.u + 0x7fffu + ((v.u >> 16) & 1u);  // RNE
    return (unsigned short)(r >> 16);
}
static __device__ __forceinline__ float bf2f(unsigned short u) {
    union { unsigned int u; float f; } v; v.u = ((unsigned int)u) << 16;
    return v.f;
}
static __device__ __forceinline__ bf16x8 ldbf8(const unsigned short* p) {
    u16x8 u = *(const u16x8*)p;
    return __builtin_bit_cast(bf16x8, u);
}
static __device__ __forceinline__ unsigned int cvtpk(float lo, float hi) {
    unsigned int d;
    asm("v_cvt_pk_bf16_f32 %0, %1, %2" : "=v"(d) : "v"(lo), "v"(hi));
    return d;
}

// ---------------- GroupNorm statistics (two-stage, deterministic) ------------
__global__ __launch_bounds__(256) void k_stats_partial(const float* __restrict__ x,
                                                       float* __restrict__ part) {
    int bg = blockIdx.x >> 5;
    int p  = blockIdx.x & 31;
    const float4* base = (const float4*)(x + (size_t)bg * 131072 + (size_t)p * 4096);
    float s = 0.f, s2 = 0.f;
#pragma unroll
    for (int i = 0; i < 4; ++i) {
        float4 v = base[threadIdx.x + i * 256];
        s  += v.x + v.y + v.z + v.w;
        s2 += v.x * v.x + v.y * v.y + v.z * v.z + v.w * v.w;
    }
    __shared__ float ss[256], sq[256];
    ss[threadIdx.x] = s; sq[threadIdx.x] = s2;
    __syncthreads();
    for (int off = 128; off > 0; off >>= 1) {
        if (threadIdx.x < off) {
            ss[threadIdx.x] += ss[threadIdx.x + off];
            sq[threadIdx.x] += sq[threadIdx.x + off];
        }
        __syncthreads();
    }
    if (threadIdx.x == 0) {
        part[blockIdx.x * 2 + 0] = ss[0];
        part[blockIdx.x * 2 + 1] = sq[0];
    }
}

__global__ __launch_bounds__(64) void k_stats_final(const float* __restrict__ part,
                                                    float* __restrict__ stats) {
    int bg = blockIdx.x;
    float s = 0.f, s2 = 0.f;
    if (threadIdx.x < 32) {
        s  = part[(bg * 32 + threadIdx.x) * 2 + 0];
        s2 = part[(bg * 32 + threadIdx.x) * 2 + 1];
    }
#pragma unroll
    for (int off = 16; off > 0; off >>= 1) {
        s  += __shfl_down(s, off);
        s2 += __shfl_down(s2, off);
    }
    if (threadIdx.x == 0) {
        const float inv = 1.0f / 131072.0f;
        float mean = s * inv;
        float var  = s2 * inv - mean * mean;
        stats[bg * 2 + 0] = mean;
        stats[bg * 2 + 1] = rsqrtf(var + EPSV);
    }
}

// ---------------- QKV projection GEMM (fp32 core, bf16 transposed epilogue) --
__global__ __launch_bounds__(256) void k_qkv(const float* __restrict__ x,
                                             const float* __restrict__ wqkv,
                                             const float* __restrict__ nw,
                                             const float* __restrict__ nbias,
                                             const float* __restrict__ stats,
                                             unsigned short* __restrict__ qkT,
                                             unsigned short* __restrict__ vbf) {
    __shared__ float As[32][68];
    __shared__ float Bs[32][68];
    int b = blockIdx.z, o0 = blockIdx.y * 64, n0 = blockIdx.x * 64;
    int tid = threadIdx.x, tx = tid & 15, ty = tid >> 4;
    float acc[4][4] = {};
    for (int c0 = 0; c0 < NC; c0 += 32) {
        int g = c0 >> 5;
        float mean = stats[(b * NG + g) * 2 + 0];
        float rstd = stats[(b * NG + g) * 2 + 1];
#pragma unroll
        for (int r = 0; r < 8; ++r) {
            int idx = r * 256 + tid;
            int ol = idx >> 5, cl = idx & 31;
            As[cl][ol] = wqkv[(size_t)(o0 + ol) * NC + c0 + cl];
        }
#pragma unroll
        for (int r = 0; r < 8; ++r) {
            int idx = r * 256 + tid;
            int cl = idx >> 6, nl = idx & 63;
            int c = c0 + cl;
            float v = x[((size_t)(b * NC + c)) * NT + n0 + nl];
            Bs[cl][nl] = (v - mean) * rstd * nw[c] + nbias[c];
        }
        __syncthreads();
#pragma unroll
        for (int k = 0; k < 32; ++k) {
            float4 a = *(const float4*)&As[k][ty * 4];
            float4 bv = *(const float4*)&Bs[k][tx * 4];
            float av[4] = {a.x, a.y, a.z, a.w};
            float bw[4] = {bv.x, bv.y, bv.z, bv.w};
#pragma unroll
            for (int i = 0; i < 4; ++i)
#pragma unroll
                for (int j = 0; j < 4; ++j)
                    acc[i][j] += av[i] * bw[j];
        }
        __syncthreads();
    }
    if (blockIdx.y < 8) {
        int o = o0 + ty * 4;
        int qk = o >> 8;
        int hh = (o >> 5) & 7;
        int d4 = o & 31;
        float sc = (qk == 0) ? SCALE_L2E : 1.0f;
        unsigned short* dst = qkT + ((((size_t)qk * NB + b) * NH + hh) * NT) * 32;
#pragma unroll
        for (int j = 0; j < 4; ++j) {
            int tok = n0 + tx * 4 + j;
            u16x4 pk = { f2bf(acc[0][j] * sc), f2bf(acc[1][j] * sc),
                         f2bf(acc[2][j] * sc), f2bf(acc[3][j] * sc) };
            *(u16x4*)&dst[(size_t)tok * 32 + d4] = pk;
        }
    } else {
        int o = o0 + ty * 4;
        int hh = (o >> 5) & 7;
        int d = o & 31;
        unsigned short* dst = vbf + (((size_t)b * NH + hh) * 32) * NT;
#pragma unroll
        for (int i = 0; i < 4; ++i) {
            u16x4 pk = { f2bf(acc[i][0]), f2bf(acc[i][1]),
                         f2bf(acc[i][2]), f2bf(acc[i][3]) };
            *(u16x4*)&dst[(size_t)(d + i) * NT + n0 + tx * 4] = pk;
        }
    }
}

// ---------------- Attention: swapped-QK^T bf16 MFMA, split-token -------------
// 1-D grid 2048 blocks, 256 threads = 4 waves; wave owns 32 queries.
// XCD-aware remap: all 32 query-blocks of one (b,h,ch) combo share one XCD
// (1 MB K/V working set per XCD -> L2-resident). K/V tile (32 tok) staged in
// LDS once per block -> global read volume /4 vs per-wave loads.
// SIMPLE staging schedule (correctness-first): single buffer, two barriers.
// P redistribution in-register: 2x permlane32_swap + 2x ds_swizzle(xor16).
__global__ __launch_bounds__(256) void k_attn(const unsigned short* __restrict__ qkT,
                                              const unsigned short* __restrict__ vbf,
                                              unsigned short* __restrict__ pO,
                                              float* __restrict__ pl) {
    __shared__ unsigned short KV[2048];   // [0,1024)=K[tok][d], [1024,2048)=V[d][tok]
    int bid = blockIdx.x;
    int xcd  = bid & 7;
    int slot = bid >> 3;                 // 0..255
    int combo = xcd * 8 + (slot >> 5);   // 0..63: all sb of a combo on one XCD
    int sb    = slot & 31;
    int b  = combo >> 5;
    int ch = (combo >> 3) & 3;
    int h  = combo & 7;

    int tid = threadIdx.x;
    int w = tid >> 6, lane = tid & 63, col = lane & 15, g = lane >> 4;
    bool b4 = (g & 1) != 0;
    int s0 = sb * 128 + w * 32;

    const unsigned short* qB = qkT + ((((size_t)0 * NB + b) * NH + h) * NT) * 32;
    const unsigned short* kB = qkT + ((((size_t)1 * NB + b) * NH + h) * NT) * 32;
    const unsigned short* vB = vbf + (((size_t)b * NH + h) * 32) * NT;

    // Q fragments (B-operand): col = s, k = d = g*8+j. Scale pre-folded.
    bf16x8 qf[2];
    qf[0] = ldbf8(qB + (size_t)(s0 + col) * 32 + g * 8);
    qf[1] = ldbf8(qB + (size_t)(s0 + 16 + col) * 32 + g * 8);

    u16x8 ou;
#pragma unroll
    for (int j = 0; j < 8; ++j) ou[j] = 0x3F80;  // bf16 1.0
    const bf16x8 ones = __builtin_bit_cast(bf16x8, ou);

    // Staging source: 16B per thread per iteration.
    // tid<128: K tile (contiguous 2KB in global); tid>=128: V tile rows.
    const unsigned short* gs;
    int gstep;
    if (tid < 128) {
        gs = kB + ((size_t)ch * CHTOK) * 32 + tid * 8;
        gstep = 1024;                    // 32 tokens * 32 d
    } else {
        int idx = tid - 128;
        int d = idx >> 2, tq = (idx & 3) * 8;
        gs = vB + (size_t)d * NT + ch * CHTOK + tq;
        gstep = 32;                      // 32 tokens
    }

    f32x4 oacc[2][2] = {};     // [d-tile][s-tile]
    f32x4 lacc[2] = {};        // [s-tile] partial softmax denominator

    for (int it = 0; it < NIT; ++it) {
        __syncthreads();   // all reads of previous tile complete
        *(u16x8*)&KV[tid * 8] = *(const u16x8*)(gs + (size_t)it * gstep);
        __syncthreads();   // tile fully staged
        bf16x8 k0 = ldbf8(&KV[0] + col * 32 + g * 8);
        bf16x8 k1 = ldbf8(&KV[0] + (16 + col) * 32 + g * 8);
        bf16x8 v0 = ldbf8(&KV[0] + 1024 + col * 32 + g * 8);
        bf16x8 v1 = ldbf8(&KV[0] + 1024 + (16 + col) * 32 + g * 8);
        const f32x4 z = {0.f, 0.f, 0.f, 0.f};
#pragma unroll
        for (int st = 0; st < 2; ++st) {
            // S^T tiles: rows t (k0: t 0-15, k1: t 16-31), col s. Lane: rows g*4+r.
            f32x4 sa = __builtin_amdgcn_mfma_f32_16x16x32_bf16(k0, qf[st], z, 0, 0, 0);
            f32x4 sb2 = __builtin_amdgcn_mfma_f32_16x16x32_bf16(k1, qf[st], z, 0, 0, 0);
            // no-max softmax (logits bounded): P = exp2(S)
            unsigned int W0 = cvtpk(__builtin_amdgcn_exp2f(sa[0]),
                                    __builtin_amdgcn_exp2f(sa[1]));   // unit g*2
            unsigned int W1 = cvtpk(__builtin_amdgcn_exp2f(sa[2]),
                                    __builtin_amdgcn_exp2f(sa[3]));   // unit g*2+1
            unsigned int W2 = cvtpk(__builtin_amdgcn_exp2f(sb2[0]),
                                    __builtin_amdgcn_exp2f(sb2[1]));  // unit 8+g*2
            unsigned int W3 = cvtpk(__builtin_amdgcn_exp2f(sb2[2]),
                                    __builtin_amdgcn_exp2f(sb2[3]));  // unit 8+g*2+1
            // stage A: swap across lane bit5
            unsigned int o0 = W0, o1 = W2;
            asm("v_permlane32_swap_b32 %0, %1" : "+v"(o0), "+v"(o1));
            unsigned int e0 = W1, e1 = W3;
            asm("v_permlane32_swap_b32 %0, %1" : "+v"(e0), "+v"(e1));
            // stage B: exchange with bit4 neighbor
            unsigned int vo = b4 ? o0 : o1;
            unsigned int ve = b4 ? e0 : e1;
            unsigned int svo = (unsigned int)__builtin_amdgcn_ds_swizzle((int)vo, 0x401F);
            unsigned int sve = (unsigned int)__builtin_amdgcn_ds_swizzle((int)ve, 0x401F);
            // B-fragment words j=0..3 = units 4g+j (t rows g*8 .. g*8+7)
            u32x4 pbw = { b4 ? svo : o0, b4 ? sve : e0,
                          b4 ? o1 : svo, b4 ? e1 : sve };
            bf16x8 pf = __builtin_bit_cast(bf16x8, pbw);
            lacc[st]    = __builtin_amdgcn_mfma_f32_16x16x32_bf16(ones, pf, lacc[st], 0, 0, 0);
            oacc[0][st] = __builtin_amdgcn_mfma_f32_16x16x32_bf16(v0, pf, oacc[0][st], 0, 0, 0);
            oacc[1][st] = __builtin_amdgcn_mfma_f32_16x16x32_bf16(v1, pf, oacc[1][st], 0, 0, 0);
        }
    }

    unsigned short* pOc = pO + (size_t)ch * PO_ELEMS;
#pragma unroll
    for (int dt = 0; dt < 2; ++dt)
#pragma unroll
        for (int st = 0; st < 2; ++st) {
            int s = s0 + st * 16 + col;
            unsigned int u0 = cvtpk(oacc[dt][st][0], oacc[dt][st][1]);
            unsigned int u1 = cvtpk(oacc[dt][st][2], oacc[dt][st][3]);
            size_t base = ((size_t)(b * NC + h * 32 + dt * 16 + g * 4)) * NT + s;
            pOc[base]          = (unsigned short)(u0 & 0xFFFF);
            pOc[base + NT]     = (unsigned short)(u0 >> 16);
            pOc[base + 2 * NT] = (unsigned short)(u1 & 0xFFFF);
            pOc[base + 3 * NT] = (unsigned short)(u1 >> 16);
        }
    if (g == 0) {
#pragma unroll
        for (int st = 0; st < 2; ++st) {
            int s = s0 + st * 16 + col;
            pl[(((size_t)ch * NB + b) * NH + h) * NT + s] = lacc[st][0];
        }
    }
}

// ---------------- Combine partial chunks: att = sum(O) / sum(l) (bf16) -------
__global__ __launch_bounds__(256) void k_combine(const unsigned short* __restrict__ pO,
                                                 const float* __restrict__ pl,
                                                 unsigned short* __restrict__ att) {
    int f = blockIdx.x * 256 + threadIdx.x;   // quad index, 524288 total
    int b  = f >> 18;
    int r  = f & 262143;
    int c  = r >> 10;
    int sq = (r & 1023) * 4;
    int h  = c >> 5;
    float num[4] = {0.f, 0.f, 0.f, 0.f};
    float den[4] = {0.f, 0.f, 0.f, 0.f};
#pragma unroll
    for (int chn = 0; chn < NCHUNK; ++chn) {
        u16x4 ov = *(const u16x4*)&pO[(size_t)chn * PO_ELEMS + (size_t)f * 4];
        float4 lv = *(const float4*)&pl[(((size_t)chn * NB + b) * NH + h) * NT + sq];
        num[0] += bf2f(ov[0]); num[1] += bf2f(ov[1]);
        num[2] += bf2f(ov[2]); num[3] += bf2f(ov[3]);
        den[0] += lv.x; den[1] += lv.y; den[2] += lv.z; den[3] += lv.w;
    }
    u16x4 res = { f2bf(num[0] / den[0]), f2bf(num[1] / den[1]),
                  f2bf(num[2] / den[2]), f2bf(num[3] / den[3]) };
    *(u16x4*)&att[(size_t)f * 4] = res;
}

// ---------------- Output projection GEMM + bias + residual (bf16 att in) -----
__global__ __launch_bounds__(256) void k_out(const unsigned short* __restrict__ att,
                                             const float* __restrict__ wout,
                                             const float* __restrict__ bout,
                                             const float* __restrict__ x,
                                             float* __restrict__ out) {
    __shared__ float As[32][68];
    __shared__ float Bs[32][68];
    int b = blockIdx.z, o0 = blockIdx.y * 64, n0 = blockIdx.x * 64;
    int tid = threadIdx.x, tx = tid & 15, ty = tid >> 4;
    float acc[4][4] = {};
    for (int c0 = 0; c0 < NC; c0 += 32) {
#pragma unroll
        for (int r = 0; r < 8; ++r) {
            int idx = r * 256 + tid;
            int ol = idx >> 5, cl = idx & 31;
            As[cl][ol] = wout[(size_t)(o0 + ol) * NC + c0 + cl];
        }
#pragma unroll
        for (int r = 0; r < 2; ++r) {
            int q = r * 256 + tid;
            int cl = q >> 4, nq = (q & 15) * 4;
            u16x4 v4 = *(const u16x4*)&att[((size_t)(b * NC + c0 + cl)) * NT + n0 + nq];
            Bs[cl][nq + 0] = bf2f(v4[0]);
            Bs[cl][nq + 1] = bf2f(v4[1]);
            Bs[cl][nq + 2] = bf2f(v4[2]);
            Bs[cl][nq + 3] = bf2f(v4[3]);
        }
        __syncthreads();
#pragma unroll
        for (int k = 0; k < 32; ++k) {
            float4 a = *(const float4*)&As[k][ty * 4];
            float4 bv = *(const float4*)&Bs[k][tx * 4];
            float av[4] = {a.x, a.y, a.z, a.w};
            float bw[4] = {bv.x, bv.y, bv.z, bv.w};
#pragma unroll
            for (int i = 0; i < 4; ++i)
#pragma unroll
                for (int j = 0; j < 4; ++j)
                    acc[i][j] += av[i] * bw[j];
        }
        __syncthreads();
    }
#pragma unroll
    for (int i = 0; i < 4; ++i) {
        int o = o0 + ty * 4 + i;
        float bo = bout[o];
        size_t rowoff = ((size_t)(b * NC + o)) * NT + n0 + tx * 4;
        float4 xr = *(const float4*)&x[rowoff];
        float4 st = {acc[i][0] + bo + xr.x, acc[i][1] + bo + xr.y,
                     acc[i][2] + bo + xr.z, acc[i][3] + bo + xr.w};
        *(float4*)&out[rowoff] = st;
    }
}

extern "C" void kernel_launch(void* const* d_in, const int* in_sizes, int n_in,
                              void* d_out, int out_size, void* d_ws, size_t ws_size,
                              hipStream_t stream) {
    const float* x    = (const float*)d_in[0];
    const float* nw   = (const float*)d_in[1];
    const float* nb   = (const float*)d_in[2];
    const float* wqkv = (const float*)d_in[3];
    const float* wout = (const float*)d_in[4];
    const float* bout = (const float*)d_in[5];
    float* out = (float*)d_out;
    char* wsb = (char*)d_ws;

    unsigned short* qkT = (unsigned short*)wsb;                        // 8 MB: [2][B][H][4096][32] bf16
    unsigned short* vbf = (unsigned short*)(wsb + 8u * 1024 * 1024);   // 4 MB: [B][H][32][4096] bf16
    unsigned short* pO  = (unsigned short*)(wsb + 12u * 1024 * 1024);  // 16 MB: [4ch][B][C][N] bf16
    float* pl   = (float*)(wsb + 28u * 1024 * 1024);                   // 1 MB: [4ch][B][H][N] f32
    float* part = (float*)(wsb + 29u * 1024 * 1024);
    float* stats = part + 1024;
    // att (bf16, 4 MB) aliases the dead qkT region: k_attn finished reading
    // qkT before k_combine writes it; k_qkv rewrites qkT fully every call.
    unsigned short* att = qkT;

    k_stats_partial<<<512, 256, 0, stream>>>(x, part);
    k_stats_final<<<16, 64, 0, stream>>>(part, stats);
    k_qkv<<<dim3(NT / 64, 768 / 64, NB), 256, 0, stream>>>(x, wqkv, nw, nb, stats, qkT, vbf);
    k_attn<<<dim3(NB * NCHUNK * NH * 32), 256, 0, stream>>>(qkT, vbf, pO, pl);
    k_combine<<<2048, 256, 0, stream>>>(pO, pl, att);
    k_out<<<dim3(NT / 64, NC / 64, NB), 256, 0, stream>>>(att, wout, bout, x, out);
}

// Round 9
// 135.122 us; speedup vs baseline: 1.3712x; 1.1871x over previous
//
#include <hip/hip_runtime.h>

// B=2, C=256, X=Y=Z=16 -> N=4096, GROUPS=8, HEADS=8, D=32
#define NB 2
#define NC 256
#define NT 4096
#define NG 8
#define NH 8
#define EPSV 1e-5f
// (1/sqrt(32)) * log2(e): folded into Q at projection time -> softmax is exp2()
#define SCALE_L2E 0.25503164427f
#define NCHUNK 4
#define CHTOK (NT / NCHUNK)                 // 1024 tokens per chunk
#define NIT (CHTOK / 32)                    // 32 iterations per chunk
#define PO_ELEMS ((size_t)NB * NC * NT)     // bf16 elements per chunk of partial O

typedef __attribute__((ext_vector_type(8))) __bf16 bf16x8;
typedef __attribute__((ext_vector_type(8))) unsigned short u16x8;
typedef __attribute__((ext_vector_type(4))) unsigned short u16x4;
typedef __attribute__((ext_vector_type(4))) unsigned int u32x4;
typedef __attribute__((ext_vector_type(4))) float f32x4;

static __device__ __forceinline__ unsigned short f2bf(float f) {
    union { float f; unsigned int u; } v; v.f = f;
    unsigned int r = v.u + 0x7fffu + ((v.u >> 16) & 1u);  // RNE
    return (unsigned short)(r >> 16);
}
static __device__ __forceinline__ float bf2f(unsigned short u) {
    union { unsigned int u; float f; } v; v.u = ((unsigned int)u) << 16;
    return v.f;
}
static __device__ __forceinline__ bf16x8 ldbf8(const unsigned short* p) {
    u16x8 u = *(const u16x8*)p;
    return __builtin_bit_cast(bf16x8, u);
}
static __device__ __forceinline__ unsigned int cvtpk(float lo, float hi) {
    unsigned int d;
    asm("v_cvt_pk_bf16_f32 %0, %1, %2" : "=v"(d) : "v"(lo), "v"(hi));
    return d;
}

// ---------------- GroupNorm statistics (two-stage, deterministic) ------------
__global__ __launch_bounds__(256) void k_stats_partial(const float* __restrict__ x,
                                                       float* __restrict__ part) {
    int bg = blockIdx.x >> 5;
    int p  = blockIdx.x & 31;
    const float4* base = (const float4*)(x + (size_t)bg * 131072 + (size_t)p * 4096);
    float s = 0.f, s2 = 0.f;
#pragma unroll
    for (int i = 0; i < 4; ++i) {
        float4 v = base[threadIdx.x + i * 256];
        s  += v.x + v.y + v.z + v.w;
        s2 += v.x * v.x + v.y * v.y + v.z * v.z + v.w * v.w;
    }
    __shared__ float ss[256], sq[256];
    ss[threadIdx.x] = s; sq[threadIdx.x] = s2;
    __syncthreads();
    for (int off = 128; off > 0; off >>= 1) {
        if (threadIdx.x < off) {
            ss[threadIdx.x] += ss[threadIdx.x + off];
            sq[threadIdx.x] += sq[threadIdx.x + off];
        }
        __syncthreads();
    }
    if (threadIdx.x == 0) {
        part[blockIdx.x * 2 + 0] = ss[0];
        part[blockIdx.x * 2 + 1] = sq[0];
    }
}

__global__ __launch_bounds__(64) void k_stats_final(const float* __restrict__ part,
                                                    float* __restrict__ stats) {
    int bg = blockIdx.x;
    float s = 0.f, s2 = 0.f;
    if (threadIdx.x < 32) {
        s  = part[(bg * 32 + threadIdx.x) * 2 + 0];
        s2 = part[(bg * 32 + threadIdx.x) * 2 + 1];
    }
#pragma unroll
    for (int off = 16; off > 0; off >>= 1) {
        s  += __shfl_down(s, off);
        s2 += __shfl_down(s2, off);
    }
    if (threadIdx.x == 0) {
        const float inv = 1.0f / 131072.0f;
        float mean = s * inv;
        float var  = s2 * inv - mean * mean;
        stats[bg * 2 + 0] = mean;
        stats[bg * 2 + 1] = rsqrtf(var + EPSV);
    }
}

// ---------------- Weight prep: w_qkv fp32 -> bf16 ----------------------------
__global__ __launch_bounds__(256) void k_wprep(const float* __restrict__ wq,
                                               unsigned short* __restrict__ wq_bf) {
    int idx = (blockIdx.x * 256 + threadIdx.x) * 8;   // 196608 total
    float4 a = *(const float4*)(wq + idx);
    float4 c = *(const float4*)(wq + idx + 4);
    u32x4 o = { cvtpk(a.x, a.y), cvtpk(a.z, a.w),
                cvtpk(c.x, c.y), cvtpk(c.z, c.w) };
    *(u32x4*)(wq_bf + idx) = o;
}

// ---------------- x prep: GroupNorm + bf16 + transpose -> xnT[b][n][c] -------
__global__ __launch_bounds__(256) void k_xprep(const float* __restrict__ x,
                                               const float* __restrict__ nw,
                                               const float* __restrict__ nbias,
                                               const float* __restrict__ stats,
                                               unsigned short* __restrict__ xnT) {
    __shared__ unsigned short T[64][72];   // [n][c], padded (144B rows, 16B-aligned)
    int b = blockIdx.z, c0 = blockIdx.y * 64, n0 = blockIdx.x * 64;
    int tid = threadIdx.x;
    int c_l = tid >> 2, nq = (tid & 3) * 16;
    int c = c0 + c_l;
    int grp = c >> 5;
    float mean = stats[(b * NG + grp) * 2 + 0];
    float rstd = stats[(b * NG + grp) * 2 + 1];
    float wsc = nw[c] * rstd;
    float bb  = nbias[c] - mean * wsc;    // xn = x*wsc + bb
    const float4* src = (const float4*)(x + ((size_t)(b * NC + c)) * NT + n0 + nq);
#pragma unroll
    for (int i = 0; i < 4; ++i) {
        float4 v = src[i];
        T[nq + i * 4 + 0][c_l] = f2bf(v.x * wsc + bb);
        T[nq + i * 4 + 1][c_l] = f2bf(v.y * wsc + bb);
        T[nq + i * 4 + 2][c_l] = f2bf(v.z * wsc + bb);
        T[nq + i * 4 + 3][c_l] = f2bf(v.w * wsc + bb);
    }
    __syncthreads();
    int n_l = tid >> 2, cq = (tid & 3) * 16;
    unsigned short* dst = xnT + ((size_t)b * NT + n0 + n_l) * 256 + c0 + cq;
    *(u16x8*)dst       = *(const u16x8*)&T[n_l][cq];
    *(u16x8*)(dst + 8) = *(const u16x8*)&T[n_l][cq + 8];
}

// ---------------- QKV projection: bf16 MFMA ----------------------------------
// grid (64 n-blocks, 12 o-blocks, NB). Wave w owns 16 tokens (n0+w*16..+16),
// 64 outputs (o0..o0+64). A = weights (row o), B = xnT (col n), K = C = 256.
// Epilogue: o-blocks 0-3 -> Q (scaled), 4-7 -> K (both qkT[tok][d]),
// 8-11 -> V (vbf[d][tok]).
__global__ __launch_bounds__(256) void k_qkv_mfma(const unsigned short* __restrict__ wq_bf,
                                                  const unsigned short* __restrict__ xnT,
                                                  unsigned short* __restrict__ qkT,
                                                  unsigned short* __restrict__ vbf) {
    int b = blockIdx.z, o0 = blockIdx.y * 64, n0 = blockIdx.x * 64;
    int tid = threadIdx.x;
    int w = tid >> 6, lane = tid & 63, c16 = lane & 15, g = lane >> 4;
    int n_tok = n0 + w * 16 + c16;
    const unsigned short* Bsrc = xnT + ((size_t)b * NT + n_tok) * 256 + g * 8;
    const unsigned short* Asrc = wq_bf + (size_t)(o0 + c16) * 256 + g * 8;
    f32x4 acc[4] = {};
    for (int kk = 0; kk < 8; ++kk) {
        bf16x8 bfr = ldbf8(Bsrc + kk * 32);
#pragma unroll
        for (int ot = 0; ot < 4; ++ot) {
            bf16x8 afr = ldbf8(Asrc + ot * 16 * 256 + kk * 32);
            acc[ot] = __builtin_amdgcn_mfma_f32_16x16x32_bf16(afr, bfr, acc[ot], 0, 0, 0);
        }
    }
    if (o0 < 512) {
        int qk = o0 >> 8;
        float sc = (qk == 0) ? SCALE_L2E : 1.0f;
#pragma unroll
        for (int ot = 0; ot < 4; ++ot) {
            int ob = o0 + ot * 16 + g * 4;   // 4 consecutive d via regs
            int h  = (ob >> 5) & 7;
            int d4 = ob & 31;
            unsigned int u0 = cvtpk(acc[ot][0] * sc, acc[ot][1] * sc);
            unsigned int u1 = cvtpk(acc[ot][2] * sc, acc[ot][3] * sc);
            u16x4 pk = { (unsigned short)(u0 & 0xFFFF), (unsigned short)(u0 >> 16),
                         (unsigned short)(u1 & 0xFFFF), (unsigned short)(u1 >> 16) };
            *(u16x4*)(qkT + ((((size_t)qk * NB + b) * NH + h) * NT + n_tok) * 32 + d4) = pk;
        }
    } else {
#pragma unroll
        for (int ot = 0; ot < 4; ++ot) {
            int ob = (o0 - 512) + ot * 16 + g * 4;
            int h = (ob >> 5) & 7;
            int d = ob & 31;
            unsigned short* dst = vbf + (((size_t)b * NH + h) * 32 + d) * NT + n_tok;
            dst[0]      = f2bf(acc[ot][0]);
            dst[NT]     = f2bf(acc[ot][1]);
            dst[2 * NT] = f2bf(acc[ot][2]);
            dst[3 * NT] = f2bf(acc[ot][3]);
        }
    }
}

// ---------------- Attention: swapped-QK^T bf16 MFMA, split-token -------------
// (unchanged from passing round-8 version)
__global__ __launch_bounds__(256) void k_attn(const unsigned short* __restrict__ qkT,
                                              const unsigned short* __restrict__ vbf,
                                              unsigned short* __restrict__ pO,
                                              float* __restrict__ pl) {
    __shared__ unsigned short KV[2048];   // [0,1024)=K[tok][d], [1024,2048)=V[d][tok]
    int bid = blockIdx.x;
    int xcd  = bid & 7;
    int slot = bid >> 3;                 // 0..255
    int combo = xcd * 8 + (slot >> 5);   // 0..63: all sb of a combo on one XCD
    int sb    = slot & 31;
    int b  = combo >> 5;
    int ch = (combo >> 3) & 3;
    int h  = combo & 7;

    int tid = threadIdx.x;
    int w = tid >> 6, lane = tid & 63, col = lane & 15, g = lane >> 4;
    bool b4 = (g & 1) != 0;
    int s0 = sb * 128 + w * 32;

    const unsigned short* qB = qkT + ((((size_t)0 * NB + b) * NH + h) * NT) * 32;
    const unsigned short* kB = qkT + ((((size_t)1 * NB + b) * NH + h) * NT) * 32;
    const unsigned short* vB = vbf + (((size_t)b * NH + h) * 32) * NT;

    bf16x8 qf[2];
    qf[0] = ldbf8(qB + (size_t)(s0 + col) * 32 + g * 8);
    qf[1] = ldbf8(qB + (size_t)(s0 + 16 + col) * 32 + g * 8);

    u16x8 ou;
#pragma unroll
    for (int j = 0; j < 8; ++j) ou[j] = 0x3F80;  // bf16 1.0
    const bf16x8 ones = __builtin_bit_cast(bf16x8, ou);

    const unsigned short* gs;
    int gstep;
    if (tid < 128) {
        gs = kB + ((size_t)ch * CHTOK) * 32 + tid * 8;
        gstep = 1024;
    } else {
        int idx = tid - 128;
        int d = idx >> 2, tq = (idx & 3) * 8;
        gs = vB + (size_t)d * NT + ch * CHTOK + tq;
        gstep = 32;
    }

    f32x4 oacc[2][2] = {};
    f32x4 lacc[2] = {};

    for (int it = 0; it < NIT; ++it) {
        __syncthreads();
        *(u16x8*)&KV[tid * 8] = *(const u16x8*)(gs + (size_t)it * gstep);
        __syncthreads();
        bf16x8 k0 = ldbf8(&KV[0] + col * 32 + g * 8);
        bf16x8 k1 = ldbf8(&KV[0] + (16 + col) * 32 + g * 8);
        bf16x8 v0 = ldbf8(&KV[0] + 1024 + col * 32 + g * 8);
        bf16x8 v1 = ldbf8(&KV[0] + 1024 + (16 + col) * 32 + g * 8);
        const f32x4 z = {0.f, 0.f, 0.f, 0.f};
#pragma unroll
        for (int st = 0; st < 2; ++st) {
            f32x4 sa = __builtin_amdgcn_mfma_f32_16x16x32_bf16(k0, qf[st], z, 0, 0, 0);
            f32x4 sb2 = __builtin_amdgcn_mfma_f32_16x16x32_bf16(k1, qf[st], z, 0, 0, 0);
            unsigned int W0 = cvtpk(__builtin_amdgcn_exp2f(sa[0]),
                                    __builtin_amdgcn_exp2f(sa[1]));
            unsigned int W1 = cvtpk(__builtin_amdgcn_exp2f(sa[2]),
                                    __builtin_amdgcn_exp2f(sa[3]));
            unsigned int W2 = cvtpk(__builtin_amdgcn_exp2f(sb2[0]),
                                    __builtin_amdgcn_exp2f(sb2[1]));
            unsigned int W3 = cvtpk(__builtin_amdgcn_exp2f(sb2[2]),
                                    __builtin_amdgcn_exp2f(sb2[3]));
            unsigned int o0 = W0, o1 = W2;
            asm("v_permlane32_swap_b32 %0, %1" : "+v"(o0), "+v"(o1));
            unsigned int e0 = W1, e1 = W3;
            asm("v_permlane32_swap_b32 %0, %1" : "+v"(e0), "+v"(e1));
            unsigned int vo = b4 ? o0 : o1;
            unsigned int ve = b4 ? e0 : e1;
            unsigned int svo = (unsigned int)__builtin_amdgcn_ds_swizzle((int)vo, 0x401F);
            unsigned int sve = (unsigned int)__builtin_amdgcn_ds_swizzle((int)ve, 0x401F);
            u32x4 pbw = { b4 ? svo : o0, b4 ? sve : e0,
                          b4 ? o1 : svo, b4 ? e1 : sve };
            bf16x8 pf = __builtin_bit_cast(bf16x8, pbw);
            lacc[st]    = __builtin_amdgcn_mfma_f32_16x16x32_bf16(ones, pf, lacc[st], 0, 0, 0);
            oacc[0][st] = __builtin_amdgcn_mfma_f32_16x16x32_bf16(v0, pf, oacc[0][st], 0, 0, 0);
            oacc[1][st] = __builtin_amdgcn_mfma_f32_16x16x32_bf16(v1, pf, oacc[1][st], 0, 0, 0);
        }
    }

    unsigned short* pOc = pO + (size_t)ch * PO_ELEMS;
#pragma unroll
    for (int dt = 0; dt < 2; ++dt)
#pragma unroll
        for (int st = 0; st < 2; ++st) {
            int s = s0 + st * 16 + col;
            unsigned int u0 = cvtpk(oacc[dt][st][0], oacc[dt][st][1]);
            unsigned int u1 = cvtpk(oacc[dt][st][2], oacc[dt][st][3]);
            size_t base = ((size_t)(b * NC + h * 32 + dt * 16 + g * 4)) * NT + s;
            pOc[base]          = (unsigned short)(u0 & 0xFFFF);
            pOc[base + NT]     = (unsigned short)(u0 >> 16);
            pOc[base + 2 * NT] = (unsigned short)(u1 & 0xFFFF);
            pOc[base + 3 * NT] = (unsigned short)(u1 >> 16);
        }
    if (g == 0) {
#pragma unroll
        for (int st = 0; st < 2; ++st) {
            int s = s0 + st * 16 + col;
            pl[(((size_t)ch * NB + b) * NH + h) * NT + s] = lacc[st][0];
        }
    }
}

// ---------------- Combine partial chunks: att = sum(O) / sum(l) (bf16) -------
__global__ __launch_bounds__(256) void k_combine(const unsigned short* __restrict__ pO,
                                                 const float* __restrict__ pl,
                                                 unsigned short* __restrict__ att) {
    int f = blockIdx.x * 256 + threadIdx.x;   // quad index, 524288 total
    int b  = f >> 18;
    int r  = f & 262143;
    int c  = r >> 10;
    int sq = (r & 1023) * 4;
    int h  = c >> 5;
    float num[4] = {0.f, 0.f, 0.f, 0.f};
    float den[4] = {0.f, 0.f, 0.f, 0.f};
#pragma unroll
    for (int chn = 0; chn < NCHUNK; ++chn) {
        u16x4 ov = *(const u16x4*)&pO[(size_t)chn * PO_ELEMS + (size_t)f * 4];
        float4 lv = *(const float4*)&pl[(((size_t)chn * NB + b) * NH + h) * NT + sq];
        num[0] += bf2f(ov[0]); num[1] += bf2f(ov[1]);
        num[2] += bf2f(ov[2]); num[3] += bf2f(ov[3]);
        den[0] += lv.x; den[1] += lv.y; den[2] += lv.z; den[3] += lv.w;
    }
    u16x4 res = { f2bf(num[0] / den[0]), f2bf(num[1] / den[1]),
                  f2bf(num[2] / den[2]), f2bf(num[3] / den[3]) };
    *(u16x4*)&att[(size_t)f * 4] = res;
}

// ---------------- Output projection GEMM + bias + residual (bf16 att in) -----
__global__ __launch_bounds__(256) void k_out(const unsigned short* __restrict__ att,
                                             const float* __restrict__ wout,
                                             const float* __restrict__ bout,
                                             const float* __restrict__ x,
                                             float* __restrict__ out) {
    __shared__ float As[32][68];
    __shared__ float Bs[32][68];
    int b = blockIdx.z, o0 = blockIdx.y * 64, n0 = blockIdx.x * 64;
    int tid = threadIdx.x, tx = tid & 15, ty = tid >> 4;
    float acc[4][4] = {};
    for (int c0 = 0; c0 < NC; c0 += 32) {
#pragma unroll
        for (int r = 0; r < 8; ++r) {
            int idx = r * 256 + tid;
            int ol = idx >> 5, cl = idx & 31;
            As[cl][ol] = wout[(size_t)(o0 + ol) * NC + c0 + cl];
        }
#pragma unroll
        for (int r = 0; r < 2; ++r) {
            int q = r * 256 + tid;
            int cl = q >> 4, nq = (q & 15) * 4;
            u16x4 v4 = *(const u16x4*)&att[((size_t)(b * NC + c0 + cl)) * NT + n0 + nq];
            Bs[cl][nq + 0] = bf2f(v4[0]);
            Bs[cl][nq + 1] = bf2f(v4[1]);
            Bs[cl][nq + 2] = bf2f(v4[2]);
            Bs[cl][nq + 3] = bf2f(v4[3]);
        }
        __syncthreads();
#pragma unroll
        for (int k = 0; k < 32; ++k) {
            float4 a = *(const float4*)&As[k][ty * 4];
            float4 bv = *(const float4*)&Bs[k][tx * 4];
            float av[4] = {a.x, a.y, a.z, a.w};
            float bw[4] = {bv.x, bv.y, bv.z, bv.w};
#pragma unroll
            for (int i = 0; i < 4; ++i)
#pragma unroll
                for (int j = 0; j < 4; ++j)
                    acc[i][j] += av[i] * bw[j];
        }
        __syncthreads();
    }
#pragma unroll
    for (int i = 0; i < 4; ++i) {
        int o = o0 + ty * 4 + i;
        float bo = bout[o];
        size_t rowoff = ((size_t)(b * NC + o)) * NT + n0 + tx * 4;
        float4 xr = *(const float4*)&x[rowoff];
        float4 st = {acc[i][0] + bo + xr.x, acc[i][1] + bo + xr.y,
                     acc[i][2] + bo + xr.z, acc[i][3] + bo + xr.w};
        *(float4*)&out[rowoff] = st;
    }
}

extern "C" void kernel_launch(void* const* d_in, const int* in_sizes, int n_in,
                              void* d_out, int out_size, void* d_ws, size_t ws_size,
                              hipStream_t stream) {
    const float* x    = (const float*)d_in[0];
    const float* nw   = (const float*)d_in[1];
    const float* nb   = (const float*)d_in[2];
    const float* wqkv = (const float*)d_in[3];
    const float* wout = (const float*)d_in[4];
    const float* bout = (const float*)d_in[5];
    float* out = (float*)d_out;
    char* wsb = (char*)d_ws;

    unsigned short* qkT = (unsigned short*)wsb;                        // 8 MB: [2][B][H][4096][32] bf16
    unsigned short* vbf = (unsigned short*)(wsb + 8u * 1024 * 1024);   // 4 MB: [B][H][32][4096] bf16
    unsigned short* pO  = (unsigned short*)(wsb + 12u * 1024 * 1024);  // 16 MB: [4ch][B][C][N] bf16
    float* pl   = (float*)(wsb + 28u * 1024 * 1024);                   // 1 MB: [4ch][B][H][N] f32
    float* part = (float*)(wsb + 29u * 1024 * 1024);
    float* stats = part + 1024;
    // xnT (4 MB) and wq_bf (384 KB) alias the pO region: both are dead before
    // k_attn writes pO (stream-ordered). att (4 MB) aliases dead qkT region.
    unsigned short* xnT   = pO;                                        // @12 MB
    unsigned short* wq_bf = (unsigned short*)(wsb + 16u * 1024 * 1024);
    unsigned short* att = qkT;

    k_stats_partial<<<512, 256, 0, stream>>>(x, part);
    k_stats_final<<<16, 64, 0, stream>>>(part, stats);
    k_wprep<<<96, 256, 0, stream>>>(wqkv, wq_bf);
    k_xprep<<<dim3(NT / 64, NC / 64, NB), 256, 0, stream>>>(x, nw, nb, stats, xnT);
    k_qkv_mfma<<<dim3(NT / 64, 12, NB), 256, 0, stream>>>(wq_bf, xnT, qkT, vbf);
    k_attn<<<dim3(NB * NCHUNK * NH * 32), 256, 0, stream>>>(qkT, vbf, pO, pl);
    k_combine<<<2048, 256, 0, stream>>>(pO, pl, att);
    k_out<<<dim3(NT / 64, NC / 64, NB), 256, 0, stream>>>(att, wout, bout, x, out);
}

// Round 13
// 132.583 us; speedup vs baseline: 1.3975x; 1.0191x over previous
//
#include <hip/hip_runtime.h>

// B=2, C=256, X=Y=Z=16 -> N=4096, GROUPS=8, HEADS=8, D=32
#define NB 2
#define NC 256
#define NT 4096
#define NG 8
#define NH 8
#define EPSV 1e-5f
// (1/sqrt(32)) * log2(e): folded into Q at projection time -> softmax is exp2()
#define SCALE_L2E 0.25503164427f
#define NCHUNK 4
#define CHTOK (NT / NCHUNK)                 // 1024 tokens per chunk
#define NIT (CHTOK / 32)                    // 32 iterations per chunk
#define PO_ELEMS ((size_t)NB * NC * NT)     // bf16 elements per chunk of partial O

typedef __attribute__((ext_vector_type(8))) __bf16 bf16x8;
typedef __attribute__((ext_vector_type(8))) unsigned short u16x8;
typedef __attribute__((ext_vector_type(4))) unsigned short u16x4;
typedef __attribute__((ext_vector_type(4))) unsigned int u32x4;
typedef __attribute__((ext_vector_type(4))) float f32x4;

static __device__ __forceinline__ unsigned short f2bf(float f) {
    union { float f; unsigned int u; } v; v.f = f;
    unsigned int r = v.u + 0x7fffu + ((v.u >> 16) & 1u);  // RNE
    return (unsigned short)(r >> 16);
}
static __device__ __forceinline__ float bf2f(unsigned short u) {
    union { unsigned int u; float f; } v; v.u = ((unsigned int)u) << 16;
    return v.f;
}
static __device__ __forceinline__ bf16x8 ldbf8(const unsigned short* p) {
    u16x8 u = *(const u16x8*)p;
    return __builtin_bit_cast(bf16x8, u);
}
static __device__ __forceinline__ unsigned int cvtpk(float lo, float hi) {
    unsigned int d;
    asm("v_cvt_pk_bf16_f32 %0, %1, %2" : "=v"(d) : "v"(lo), "v"(hi));
    return d;
}

// ---------------- GroupNorm statistics (two-stage, deterministic) ------------
__global__ __launch_bounds__(256) void k_stats_partial(const float* __restrict__ x,
                                                       float* __restrict__ part) {
    int bg = blockIdx.x >> 5;
    int p  = blockIdx.x & 31;
    const float4* base = (const float4*)(x + (size_t)bg * 131072 + (size_t)p * 4096);
    float s = 0.f, s2 = 0.f;
#pragma unroll
    for (int i = 0; i < 4; ++i) {
        float4 v = base[threadIdx.x + i * 256];
        s  += v.x + v.y + v.z + v.w;
        s2 += v.x * v.x + v.y * v.y + v.z * v.z + v.w * v.w;
    }
    __shared__ float ss[256], sq[256];
    ss[threadIdx.x] = s; sq[threadIdx.x] = s2;
    __syncthreads();
    for (int off = 128; off > 0; off >>= 1) {
        if (threadIdx.x < off) {
            ss[threadIdx.x] += ss[threadIdx.x + off];
            sq[threadIdx.x] += sq[threadIdx.x + off];
        }
        __syncthreads();
    }
    if (threadIdx.x == 0) {
        part[blockIdx.x * 2 + 0] = ss[0];
        part[blockIdx.x * 2 + 1] = sq[0];
    }
}

__global__ __launch_bounds__(64) void k_stats_final(const float* __restrict__ part,
                                                    float* __restrict__ stats) {
    int bg = blockIdx.x;
    float s = 0.f, s2 = 0.f;
    if (threadIdx.x < 32) {
        s  = part[(bg * 32 + threadIdx.x) * 2 + 0];
        s2 = part[(bg * 32 + threadIdx.x) * 2 + 1];
    }
#pragma unroll
    for (int off = 16; off > 0; off >>= 1) {
        s  += __shfl_down(s, off);
        s2 += __shfl_down(s2, off);
    }
    if (threadIdx.x == 0) {
        const float inv = 1.0f / 131072.0f;
        float mean = s * inv;
        float var  = s2 * inv - mean * mean;
        stats[bg * 2 + 0] = mean;
        stats[bg * 2 + 1] = rsqrtf(var + EPSV);
    }
}

// ---------------- Weight prep: fp32 -> bf16 (used for w_qkv and w_out) -------
__global__ __launch_bounds__(256) void k_wprep(const float* __restrict__ wq,
                                               unsigned short* __restrict__ wq_bf) {
    int idx = (blockIdx.x * 256 + threadIdx.x) * 8;
    float4 a = *(const float4*)(wq + idx);
    float4 c = *(const float4*)(wq + idx + 4);
    u32x4 o = { cvtpk(a.x, a.y), cvtpk(a.z, a.w),
                cvtpk(c.x, c.y), cvtpk(c.z, c.w) };
    *(u32x4*)(wq_bf + idx) = o;
}

// ---------------- x prep: GroupNorm + bf16 + transpose -> xnT[b][n][c] -------
__global__ __launch_bounds__(256) void k_xprep(const float* __restrict__ x,
                                               const float* __restrict__ nw,
                                               const float* __restrict__ nbias,
                                               const float* __restrict__ stats,
                                               unsigned short* __restrict__ xnT) {
    __shared__ unsigned short T[64][72];   // [n][c], padded
    int b = blockIdx.z, c0 = blockIdx.y * 64, n0 = blockIdx.x * 64;
    int tid = threadIdx.x;
    int c_l = tid >> 2, nq = (tid & 3) * 16;
    int c = c0 + c_l;
    int grp = c >> 5;
    float mean = stats[(b * NG + grp) * 2 + 0];
    float rstd = stats[(b * NG + grp) * 2 + 1];
    float wsc = nw[c] * rstd;
    float bb  = nbias[c] - mean * wsc;    // xn = x*wsc + bb
    const float4* src = (const float4*)(x + ((size_t)(b * NC + c)) * NT + n0 + nq);
#pragma unroll
    for (int i = 0; i < 4; ++i) {
        float4 v = src[i];
        T[nq + i * 4 + 0][c_l] = f2bf(v.x * wsc + bb);
        T[nq + i * 4 + 1][c_l] = f2bf(v.y * wsc + bb);
        T[nq + i * 4 + 2][c_l] = f2bf(v.z * wsc + bb);
        T[nq + i * 4 + 3][c_l] = f2bf(v.w * wsc + bb);
    }
    __syncthreads();
    int n_l = tid >> 2, cq = (tid & 3) * 16;
    unsigned short* dst = xnT + ((size_t)b * NT + n0 + n_l) * 256 + c0 + cq;
    *(u16x8*)dst       = *(const u16x8*)&T[n_l][cq];
    *(u16x8*)(dst + 8) = *(const u16x8*)&T[n_l][cq + 8];
}

// ---------------- QKV projection: bf16 MFMA ----------------------------------
__global__ __launch_bounds__(256) void k_qkv_mfma(const unsigned short* __restrict__ wq_bf,
                                                  const unsigned short* __restrict__ xnT,
                                                  unsigned short* __restrict__ qkT,
                                                  unsigned short* __restrict__ vbf) {
    int b = blockIdx.z, o0 = blockIdx.y * 64, n0 = blockIdx.x * 64;
    int tid = threadIdx.x;
    int w = tid >> 6, lane = tid & 63, c16 = lane & 15, g = lane >> 4;
    int n_tok = n0 + w * 16 + c16;
    const unsigned short* Bsrc = xnT + ((size_t)b * NT + n_tok) * 256 + g * 8;
    const unsigned short* Asrc = wq_bf + (size_t)(o0 + c16) * 256 + g * 8;
    f32x4 acc[4] = {};
    for (int kk = 0; kk < 8; ++kk) {
        bf16x8 bfr = ldbf8(Bsrc + kk * 32);
#pragma unroll
        for (int ot = 0; ot < 4; ++ot) {
            bf16x8 afr = ldbf8(Asrc + ot * 16 * 256 + kk * 32);
            acc[ot] = __builtin_amdgcn_mfma_f32_16x16x32_bf16(afr, bfr, acc[ot], 0, 0, 0);
        }
    }
    if (o0 < 512) {
        int qk = o0 >> 8;
        float sc = (qk == 0) ? SCALE_L2E : 1.0f;
#pragma unroll
        for (int ot = 0; ot < 4; ++ot) {
            int ob = o0 + ot * 16 + g * 4;
            int h  = (ob >> 5) & 7;
            int d4 = ob & 31;
            unsigned int u0 = cvtpk(acc[ot][0] * sc, acc[ot][1] * sc);
            unsigned int u1 = cvtpk(acc[ot][2] * sc, acc[ot][3] * sc);
            u16x4 pk = { (unsigned short)(u0 & 0xFFFF), (unsigned short)(u0 >> 16),
                         (unsigned short)(u1 & 0xFFFF), (unsigned short)(u1 >> 16) };
            *(u16x4*)(qkT + ((((size_t)qk * NB + b) * NH + h) * NT + n_tok) * 32 + d4) = pk;
        }
    } else {
#pragma unroll
        for (int ot = 0; ot < 4; ++ot) {
            int ob = (o0 - 512) + ot * 16 + g * 4;
            int h = (ob >> 5) & 7;
            int d = ob & 31;
            unsigned short* dst = vbf + (((size_t)b * NH + h) * 32 + d) * NT + n_tok;
            dst[0]      = f2bf(acc[ot][0]);
            dst[NT]     = f2bf(acc[ot][1]);
            dst[2 * NT] = f2bf(acc[ot][2]);
            dst[3 * NT] = f2bf(acc[ot][3]);
        }
    }
}

// ---------------- Attention: swapped-QK^T bf16 MFMA, split-token -------------
// EXACT round-9 compute core (permlane P redistribution, linear KV LDS,
// K=32 PV, 2-barrier staging) — only the pO epilogue layout changed to
// [ch][b][n][c] (bisect: isolate the round-10 NaN to the PV/LDS deltas).
__global__ __launch_bounds__(256) void k_attn(const unsigned short* __restrict__ qkT,
                                              const unsigned short* __restrict__ vbf,
                                              unsigned short* __restrict__ pO,
                                              float* __restrict__ pl) {
    __shared__ unsigned short KV[2048];   // [0,1024)=K[tok][d], [1024,2048)=V[d][tok]
    int bid = blockIdx.x;
    int xcd  = bid & 7;
    int slot = bid >> 3;
    int combo = xcd * 8 + (slot >> 5);
    int sb    = slot & 31;
    int b  = combo >> 5;
    int ch = (combo >> 3) & 3;
    int h  = combo & 7;

    int tid = threadIdx.x;
    int w = tid >> 6, lane = tid & 63, col = lane & 15, g = lane >> 4;
    bool b4 = (g & 1) != 0;
    int s0 = sb * 128 + w * 32;

    const unsigned short* qB = qkT + ((((size_t)0 * NB + b) * NH + h) * NT) * 32;
    const unsigned short* kB = qkT + ((((size_t)1 * NB + b) * NH + h) * NT) * 32;
    const unsigned short* vB = vbf + (((size_t)b * NH + h) * 32) * NT;

    bf16x8 qf[2];
    qf[0] = ldbf8(qB + (size_t)(s0 + col) * 32 + g * 8);
    qf[1] = ldbf8(qB + (size_t)(s0 + 16 + col) * 32 + g * 8);

    u16x8 ou;
#pragma unroll
    for (int j = 0; j < 8; ++j) ou[j] = 0x3F80;  // bf16 1.0
    const bf16x8 ones = __builtin_bit_cast(bf16x8, ou);

    const unsigned short* gs;
    int gstep;
    if (tid < 128) {
        gs = kB + ((size_t)ch * CHTOK) * 32 + tid * 8;
        gstep = 1024;
    } else {
        int idx = tid - 128;
        int d = idx >> 2, tq = (idx & 3) * 8;
        gs = vB + (size_t)d * NT + ch * CHTOK + tq;
        gstep = 32;
    }

    f32x4 oacc[2][2] = {};
    f32x4 lacc[2] = {};

    for (int it = 0; it < NIT; ++it) {
        __syncthreads();
        *(u16x8*)&KV[tid * 8] = *(const u16x8*)(gs + (size_t)it * gstep);
        __syncthreads();
        bf16x8 k0 = ldbf8(&KV[0] + col * 32 + g * 8);
        bf16x8 k1 = ldbf8(&KV[0] + (16 + col) * 32 + g * 8);
        bf16x8 v0 = ldbf8(&KV[0] + 1024 + col * 32 + g * 8);
        bf16x8 v1 = ldbf8(&KV[0] + 1024 + (16 + col) * 32 + g * 8);
        const f32x4 z = {0.f, 0.f, 0.f, 0.f};
#pragma unroll
        for (int st = 0; st < 2; ++st) {
            f32x4 sa = __builtin_amdgcn_mfma_f32_16x16x32_bf16(k0, qf[st], z, 0, 0, 0);
            f32x4 sb2 = __builtin_amdgcn_mfma_f32_16x16x32_bf16(k1, qf[st], z, 0, 0, 0);
            unsigned int W0 = cvtpk(__builtin_amdgcn_exp2f(sa[0]),
                                    __builtin_amdgcn_exp2f(sa[1]));
            unsigned int W1 = cvtpk(__builtin_amdgcn_exp2f(sa[2]),
                                    __builtin_amdgcn_exp2f(sa[3]));
            unsigned int W2 = cvtpk(__builtin_amdgcn_exp2f(sb2[0]),
                                    __builtin_amdgcn_exp2f(sb2[1]));
            unsigned int W3 = cvtpk(__builtin_amdgcn_exp2f(sb2[2]),
                                    __builtin_amdgcn_exp2f(sb2[3]));
            unsigned int o0 = W0, o1 = W2;
            asm("v_permlane32_swap_b32 %0, %1" : "+v"(o0), "+v"(o1));
            unsigned int e0 = W1, e1 = W3;
            asm("v_permlane32_swap_b32 %0, %1" : "+v"(e0), "+v"(e1));
            unsigned int vo = b4 ? o0 : o1;
            unsigned int ve = b4 ? e0 : e1;
            unsigned int svo = (unsigned int)__builtin_amdgcn_ds_swizzle((int)vo, 0x401F);
            unsigned int sve = (unsigned int)__builtin_amdgcn_ds_swizzle((int)ve, 0x401F);
            u32x4 pbw = { b4 ? svo : o0, b4 ? sve : e0,
                          b4 ? o1 : svo, b4 ? e1 : sve };
            bf16x8 pf = __builtin_bit_cast(bf16x8, pbw);
            lacc[st]    = __builtin_amdgcn_mfma_f32_16x16x32_bf16(ones, pf, lacc[st], 0, 0, 0);
            oacc[0][st] = __builtin_amdgcn_mfma_f32_16x16x32_bf16(v0, pf, oacc[0][st], 0, 0, 0);
            oacc[1][st] = __builtin_amdgcn_mfma_f32_16x16x32_bf16(v1, pf, oacc[1][st], 0, 0, 0);
        }
    }

    unsigned short* pOc = pO + (size_t)ch * PO_ELEMS;   // layout [b][n][c]
#pragma unroll
    for (int dt = 0; dt < 2; ++dt)
#pragma unroll
        for (int st = 0; st < 2; ++st) {
            int s = s0 + st * 16 + col;
            unsigned int u0 = cvtpk(oacc[dt][st][0], oacc[dt][st][1]);
            unsigned int u1 = cvtpk(oacc[dt][st][2], oacc[dt][st][3]);
            u16x4 pk = { (unsigned short)(u0 & 0xFFFF), (unsigned short)(u0 >> 16),
                         (unsigned short)(u1 & 0xFFFF), (unsigned short)(u1 >> 16) };
            *(u16x4*)&pOc[((size_t)(b * NT + s)) * 256 + h * 32 + dt * 16 + g * 4] = pk;
        }
    if (g == 0) {
#pragma unroll
        for (int st = 0; st < 2; ++st) {
            int s = s0 + st * 16 + col;
            pl[(((size_t)ch * NB + b) * NH + h) * NT + s] = lacc[st][0];
        }
    }
}

// ---------------- Combine partial chunks -> attT[b][n][c] (bf16) -------------
__global__ __launch_bounds__(256) void k_combine(const unsigned short* __restrict__ pO,
                                                 const float* __restrict__ pl,
                                                 unsigned short* __restrict__ attT) {
    int f = blockIdx.x * 256 + threadIdx.x;   // quad index, 524288 total
    int b  = f >> 18;
    int r  = f & 262143;
    int s  = r >> 6;
    int cq = (r & 63) * 4;
    int h  = cq >> 5;
    float num[4] = {0.f, 0.f, 0.f, 0.f};
    float den = 0.f;
#pragma unroll
    for (int chn = 0; chn < NCHUNK; ++chn) {
        u16x4 ov = *(const u16x4*)&pO[(size_t)chn * PO_ELEMS +
                                      ((size_t)(b * NT + s)) * 256 + cq];
        den += pl[(((size_t)chn * NB + b) * NH + h) * NT + s];
        num[0] += bf2f(ov[0]); num[1] += bf2f(ov[1]);
        num[2] += bf2f(ov[2]); num[3] += bf2f(ov[3]);
    }
    float rd = 1.0f / den;
    u16x4 res = { f2bf(num[0] * rd), f2bf(num[1] * rd),
                  f2bf(num[2] * rd), f2bf(num[3] * rd) };
    *(u16x4*)&attT[((size_t)(b * NT + s)) * 256 + cq] = res;
}

// ---------------- Output projection: bf16 MFMA + bias + residual -------------
__global__ __launch_bounds__(256) void k_out_mfma(const unsigned short* __restrict__ attT,
                                                  const unsigned short* __restrict__ wo_bf,
                                                  const float* __restrict__ bout,
                                                  const float* __restrict__ x,
                                                  float* __restrict__ out) {
    int b = blockIdx.z, o0 = blockIdx.y * 64, n0 = blockIdx.x * 64;
    int tid = threadIdx.x;
    int w = tid >> 6, lane = tid & 63, c16 = lane & 15, g = lane >> 4;
    int n_tok = n0 + w * 16 + c16;
    const unsigned short* Bsrc = attT + ((size_t)b * NT + n_tok) * 256 + g * 8;
    const unsigned short* Asrc = wo_bf + (size_t)(o0 + c16) * 256 + g * 8;
    f32x4 acc[4] = {};
    for (int kk = 0; kk < 8; ++kk) {
        bf16x8 bfr = ldbf8(Bsrc + kk * 32);
#pragma unroll
        for (int ot = 0; ot < 4; ++ot) {
            bf16x8 afr = ldbf8(Asrc + ot * 16 * 256 + kk * 32);
            acc[ot] = __builtin_amdgcn_mfma_f32_16x16x32_bf16(afr, bfr, acc[ot], 0, 0, 0);
        }
    }
#pragma unroll
    for (int ot = 0; ot < 4; ++ot) {
        int ob = o0 + ot * 16 + g * 4;
#pragma unroll
        for (int rr = 0; rr < 4; ++rr) {
            int o = ob + rr;
            size_t off = ((size_t)(b * NC + o)) * NT + n_tok;
            out[off] = acc[ot][rr] + bout[o] + x[off];
        }
    }
}

extern "C" void kernel_launch(void* const* d_in, const int* in_sizes, int n_in,
                              void* d_out, int out_size, void* d_ws, size_t ws_size,
                              hipStream_t stream) {
    const float* x    = (const float*)d_in[0];
    const float* nw   = (const float*)d_in[1];
    const float* nb   = (const float*)d_in[2];
    const float* wqkv = (const float*)d_in[3];
    const float* wout = (const float*)d_in[4];
    const float* bout = (const float*)d_in[5];
    float* out = (float*)d_out;
    char* wsb = (char*)d_ws;

    unsigned short* qkT = (unsigned short*)wsb;                        // 8 MB
    unsigned short* vbf = (unsigned short*)(wsb + 8u * 1024 * 1024);   // 4 MB
    unsigned short* pO  = (unsigned short*)(wsb + 12u * 1024 * 1024);  // 16 MB: [4ch][B][N][C] bf16
    float* pl   = (float*)(wsb + 28u * 1024 * 1024);                   // 1 MB
    float* part = (float*)(wsb + 29u * 1024 * 1024);
    float* stats = part + 1024;
    unsigned short* wo_bf = (unsigned short*)(wsb + 30u * 1024 * 1024); // 128 KB
    // xnT (4 MB) and wq_bf (384 KB) alias the pO region: both dead before
    // k_attn writes pO (stream-ordered). attT (4 MB) aliases dead qkT region.
    unsigned short* xnT   = pO;                                        // @12 MB
    unsigned short* wq_bf = (unsigned short*)(wsb + 16u * 1024 * 1024);
    unsigned short* attT = qkT;

    k_stats_partial<<<512, 256, 0, stream>>>(x, part);
    k_stats_final<<<16, 64, 0, stream>>>(part, stats);
    k_wprep<<<96, 256, 0, stream>>>(wqkv, wq_bf);
    k_wprep<<<32, 256, 0, stream>>>(wout, wo_bf);
    k_xprep<<<dim3(NT / 64, NC / 64, NB), 256, 0, stream>>>(x, nw, nb, stats, xnT);
    k_qkv_mfma<<<dim3(NT / 64, 12, NB), 256, 0, stream>>>(wq_bf, xnT, qkT, vbf);
    k_attn<<<dim3(NB * NCHUNK * NH * 32), 256, 0, stream>>>(qkT, vbf, pO, pl);
    k_combine<<<2048, 256, 0, stream>>>(pO, pl, attT);
    k_out_mfma<<<dim3(NT / 64, NC / 64, NB), 256, 0, stream>>>(attT, wo_bf, bout, x, out);
}

// Round 14
// 128.078 us; speedup vs baseline: 1.4466x; 1.0352x over previous
//
#include <hip/hip_runtime.h>

// B=2, C=256, X=Y=Z=16 -> N=4096, GROUPS=8, HEADS=8, D=32
#define NB 2
#define NC 256
#define NT 4096
#define NG 8
#define NH 8
#define EPSV 1e-5f
// (1/sqrt(32)) * log2(e): folded into Q at projection time -> softmax is exp2()
#define SCALE_L2E 0.25503164427f
#define NCHUNK 4
#define CHTOK (NT / NCHUNK)                 // 1024 tokens per chunk
#define NIT (CHTOK / 32)                    // 32 iterations per chunk
#define PO_ELEMS ((size_t)NB * NC * NT)     // bf16 elements per chunk of partial O

typedef __attribute__((ext_vector_type(8))) __bf16 bf16x8;
typedef __attribute__((ext_vector_type(8))) unsigned short u16x8;
typedef __attribute__((ext_vector_type(4))) unsigned short u16x4;
typedef __attribute__((ext_vector_type(4))) unsigned int u32x4;
typedef __attribute__((ext_vector_type(2))) unsigned int u32x2;
typedef __attribute__((ext_vector_type(4))) float f32x4;

static __device__ __forceinline__ unsigned short f2bf(float f) {
    union { float f; unsigned int u; } v; v.f = f;
    unsigned int r = v.u + 0x7fffu + ((v.u >> 16) & 1u);  // RNE
    return (unsigned short)(r >> 16);
}
static __device__ __forceinline__ float bf2f(unsigned short u) {
    union { unsigned int u; float f; } v; v.u = ((unsigned int)u) << 16;
    return v.f;
}
static __device__ __forceinline__ bf16x8 ldbf8(const unsigned short* p) {
    u16x8 u = *(const u16x8*)p;
    return __builtin_bit_cast(bf16x8, u);
}
static __device__ __forceinline__ unsigned int cvtpk(float lo, float hi) {
    unsigned int d;
    asm("v_cvt_pk_bf16_f32 %0, %1, %2" : "=v"(d) : "v"(lo), "v"(hi));
    return d;
}

// ---------------- GroupNorm statistics (two-stage, deterministic) ------------
__global__ __launch_bounds__(256) void k_stats_partial(const float* __restrict__ x,
                                                       float* __restrict__ part) {
    int bg = blockIdx.x >> 5;
    int p  = blockIdx.x & 31;
    const float4* base = (const float4*)(x + (size_t)bg * 131072 + (size_t)p * 4096);
    float s = 0.f, s2 = 0.f;
#pragma unroll
    for (int i = 0; i < 4; ++i) {
        float4 v = base[threadIdx.x + i * 256];
        s  += v.x + v.y + v.z + v.w;
        s2 += v.x * v.x + v.y * v.y + v.z * v.z + v.w * v.w;
    }
    __shared__ float ss[256], sq[256];
    ss[threadIdx.x] = s; sq[threadIdx.x] = s2;
    __syncthreads();
    for (int off = 128; off > 0; off >>= 1) {
        if (threadIdx.x < off) {
            ss[threadIdx.x] += ss[threadIdx.x + off];
            sq[threadIdx.x] += sq[threadIdx.x + off];
        }
        __syncthreads();
    }
    if (threadIdx.x == 0) {
        part[blockIdx.x * 2 + 0] = ss[0];
        part[blockIdx.x * 2 + 1] = sq[0];
    }
}

__global__ __launch_bounds__(64) void k_stats_final(const float* __restrict__ part,
                                                    float* __restrict__ stats) {
    int bg = blockIdx.x;
    float s = 0.f, s2 = 0.f;
    if (threadIdx.x < 32) {
        s  = part[(bg * 32 + threadIdx.x) * 2 + 0];
        s2 = part[(bg * 32 + threadIdx.x) * 2 + 1];
    }
#pragma unroll
    for (int off = 16; off > 0; off >>= 1) {
        s  += __shfl_down(s, off);
        s2 += __shfl_down(s2, off);
    }
    if (threadIdx.x == 0) {
        const float inv = 1.0f / 131072.0f;
        float mean = s * inv;
        float var  = s2 * inv - mean * mean;
        stats[bg * 2 + 0] = mean;
        stats[bg * 2 + 1] = rsqrtf(var + EPSV);
    }
}

// ---------------- Weight prep: fp32 -> bf16 (used for w_qkv and w_out) -------
__global__ __launch_bounds__(256) void k_wprep(const float* __restrict__ wq,
                                               unsigned short* __restrict__ wq_bf) {
    int idx = (blockIdx.x * 256 + threadIdx.x) * 8;
    float4 a = *(const float4*)(wq + idx);
    float4 c = *(const float4*)(wq + idx + 4);
    u32x4 o = { cvtpk(a.x, a.y), cvtpk(a.z, a.w),
                cvtpk(c.x, c.y), cvtpk(c.z, c.w) };
    *(u32x4*)(wq_bf + idx) = o;
}

// ---------------- x prep: GroupNorm + bf16 + transpose -> xnT[b][n][c] -------
__global__ __launch_bounds__(256) void k_xprep(const float* __restrict__ x,
                                               const float* __restrict__ nw,
                                               const float* __restrict__ nbias,
                                               const float* __restrict__ stats,
                                               unsigned short* __restrict__ xnT) {
    __shared__ unsigned short T[64][72];   // [n][c], padded
    int b = blockIdx.z, c0 = blockIdx.y * 64, n0 = blockIdx.x * 64;
    int tid = threadIdx.x;
    int c_l = tid >> 2, nq = (tid & 3) * 16;
    int c = c0 + c_l;
    int grp = c >> 5;
    float mean = stats[(b * NG + grp) * 2 + 0];
    float rstd = stats[(b * NG + grp) * 2 + 1];
    float wsc = nw[c] * rstd;
    float bb  = nbias[c] - mean * wsc;    // xn = x*wsc + bb
    const float4* src = (const float4*)(x + ((size_t)(b * NC + c)) * NT + n0 + nq);
#pragma unroll
    for (int i = 0; i < 4; ++i) {
        float4 v = src[i];
        T[nq + i * 4 + 0][c_l] = f2bf(v.x * wsc + bb);
        T[nq + i * 4 + 1][c_l] = f2bf(v.y * wsc + bb);
        T[nq + i * 4 + 2][c_l] = f2bf(v.z * wsc + bb);
        T[nq + i * 4 + 3][c_l] = f2bf(v.w * wsc + bb);
    }
    __syncthreads();
    int n_l = tid >> 2, cq = (tid & 3) * 16;
    unsigned short* dst = xnT + ((size_t)b * NT + n0 + n_l) * 256 + c0 + cq;
    *(u16x8*)dst       = *(const u16x8*)&T[n_l][cq];
    *(u16x8*)(dst + 8) = *(const u16x8*)&T[n_l][cq + 8];
}

// ---------------- QKV projection: bf16 MFMA ----------------------------------
__global__ __launch_bounds__(256) void k_qkv_mfma(const unsigned short* __restrict__ wq_bf,
                                                  const unsigned short* __restrict__ xnT,
                                                  unsigned short* __restrict__ qkT,
                                                  unsigned short* __restrict__ vbf) {
    int b = blockIdx.z, o0 = blockIdx.y * 64, n0 = blockIdx.x * 64;
    int tid = threadIdx.x;
    int w = tid >> 6, lane = tid & 63, c16 = lane & 15, g = lane >> 4;
    int n_tok = n0 + w * 16 + c16;
    const unsigned short* Bsrc = xnT + ((size_t)b * NT + n_tok) * 256 + g * 8;
    const unsigned short* Asrc = wq_bf + (size_t)(o0 + c16) * 256 + g * 8;
    f32x4 acc[4] = {};
    for (int kk = 0; kk < 8; ++kk) {
        bf16x8 bfr = ldbf8(Bsrc + kk * 32);
#pragma unroll
        for (int ot = 0; ot < 4; ++ot) {
            bf16x8 afr = ldbf8(Asrc + ot * 16 * 256 + kk * 32);
            acc[ot] = __builtin_amdgcn_mfma_f32_16x16x32_bf16(afr, bfr, acc[ot], 0, 0, 0);
        }
    }
    if (o0 < 512) {
        int qk = o0 >> 8;
        float sc = (qk == 0) ? SCALE_L2E : 1.0f;
#pragma unroll
        for (int ot = 0; ot < 4; ++ot) {
            int ob = o0 + ot * 16 + g * 4;
            int h  = (ob >> 5) & 7;
            int d4 = ob & 31;
            unsigned int u0 = cvtpk(acc[ot][0] * sc, acc[ot][1] * sc);
            unsigned int u1 = cvtpk(acc[ot][2] * sc, acc[ot][3] * sc);
            u16x4 pk = { (unsigned short)(u0 & 0xFFFF), (unsigned short)(u0 >> 16),
                         (unsigned short)(u1 & 0xFFFF), (unsigned short)(u1 >> 16) };
            *(u16x4*)(qkT + ((((size_t)qk * NB + b) * NH + h) * NT + n_tok) * 32 + d4) = pk;
        }
    } else {
#pragma unroll
        for (int ot = 0; ot < 4; ++ot) {
            int ob = (o0 - 512) + ot * 16 + g * 4;
            int h = (ob >> 5) & 7;
            int d = ob & 31;
            unsigned short* dst = vbf + (((size_t)b * NH + h) * 32 + d) * NT + n_tok;
            dst[0]      = f2bf(acc[ot][0]);
            dst[NT]     = f2bf(acc[ot][1]);
            dst[2 * NT] = f2bf(acc[ot][2]);
            dst[3 * NT] = f2bf(acc[ot][3]);
        }
    }
}

// ---------------- Attention: swapped-QK^T bf16 MFMA, split-token -------------
// Round-13 proven core with two changes:
// (1) P redistribution via wave-private padded LDS (20-dword rows; write
//     2x ds_write_b64, read 1x 16B-aligned ds_read_b128; same-wave in-order
//     LDS pipe -> no barrier). Replaces permlane/ds_swizzle/cndmask chain.
// (2) Prefetch-early staging: global load for it+1 issued before compute(it);
//     vmcnt satisfied by the time the store runs in it+1 (single buffer,
//     stores strictly between the two proven barriers).
__global__ __launch_bounds__(256) void k_attn(const unsigned short* __restrict__ qkT,
                                              const unsigned short* __restrict__ vbf,
                                              unsigned short* __restrict__ pO,
                                              float* __restrict__ pl) {
    __shared__ unsigned short KV[2048];   // [0,1024)=K[tok][d], [1024,2048)=V[d][tok]
    __shared__ unsigned int Pd[4][640];   // per-wave P: 32 s-rows x 20 dwords (16 used)
    int bid = blockIdx.x;
    int xcd  = bid & 7;
    int slot = bid >> 3;
    int combo = xcd * 8 + (slot >> 5);
    int sb    = slot & 31;
    int b  = combo >> 5;
    int ch = (combo >> 3) & 3;
    int h  = combo & 7;

    int tid = threadIdx.x;
    int w = tid >> 6, lane = tid & 63, col = lane & 15, g = lane >> 4;
    int s0 = sb * 128 + w * 32;

    const unsigned short* qB = qkT + ((((size_t)0 * NB + b) * NH + h) * NT) * 32;
    const unsigned short* kB = qkT + ((((size_t)1 * NB + b) * NH + h) * NT) * 32;
    const unsigned short* vB = vbf + (((size_t)b * NH + h) * 32) * NT;

    bf16x8 qf[2];
    qf[0] = ldbf8(qB + (size_t)(s0 + col) * 32 + g * 8);
    qf[1] = ldbf8(qB + (size_t)(s0 + 16 + col) * 32 + g * 8);

    u16x8 ou;
#pragma unroll
    for (int j = 0; j < 8; ++j) ou[j] = 0x3F80;  // bf16 1.0
    const bf16x8 ones = __builtin_bit_cast(bf16x8, ou);

    const unsigned short* gs;
    int gstep;
    if (tid < 128) {
        gs = kB + ((size_t)ch * CHTOK) * 32 + tid * 8;
        gstep = 1024;
    } else {
        int idx = tid - 128;
        int d = idx >> 2, tq = (idx & 3) * 8;
        gs = vB + (size_t)d * NT + ch * CHTOK + tq;
        gstep = 32;
    }

    f32x4 oacc[2][2] = {};
    f32x4 lacc[2] = {};
    unsigned int* Pw = Pd[w];

    u16x8 stg = *(const u16x8*)gs;   // prefetch iteration 0

    for (int it = 0; it < NIT; ++it) {
        __syncthreads();   // all reads of previous tile complete
        *(u16x8*)&KV[tid * 8] = stg;
        __syncthreads();   // tile fully staged
        if (it + 1 < NIT)  // issue next load early: latency hides under compute
            stg = *(const u16x8*)(gs + (size_t)(it + 1) * gstep);
        bf16x8 k0 = ldbf8(&KV[0] + col * 32 + g * 8);
        bf16x8 k1 = ldbf8(&KV[0] + (16 + col) * 32 + g * 8);
        bf16x8 v0 = ldbf8(&KV[0] + 1024 + col * 32 + g * 8);
        bf16x8 v1 = ldbf8(&KV[0] + 1024 + (16 + col) * 32 + g * 8);
        const f32x4 z = {0.f, 0.f, 0.f, 0.f};
#pragma unroll
        for (int st = 0; st < 2; ++st) {
            int s_l = st * 16 + col;
            f32x4 sa = __builtin_amdgcn_mfma_f32_16x16x32_bf16(k0, qf[st], z, 0, 0, 0);
            f32x4 sb2 = __builtin_amdgcn_mfma_f32_16x16x32_bf16(k1, qf[st], z, 0, 0, 0);
            // no-max softmax (logits bounded): P = exp2(S)
            // C/D rows t = g*4+r -> P dword index t/2: W0,W1 = g*2,g*2+1 (t<16);
            // W2,W3 = 8+g*2, 8+g*2+1 (t>=16)
            unsigned int W0 = cvtpk(__builtin_amdgcn_exp2f(sa[0]),
                                    __builtin_amdgcn_exp2f(sa[1]));
            unsigned int W1 = cvtpk(__builtin_amdgcn_exp2f(sa[2]),
                                    __builtin_amdgcn_exp2f(sa[3]));
            unsigned int W2 = cvtpk(__builtin_amdgcn_exp2f(sb2[0]),
                                    __builtin_amdgcn_exp2f(sb2[1]));
            unsigned int W3 = cvtpk(__builtin_amdgcn_exp2f(sb2[2]),
                                    __builtin_amdgcn_exp2f(sb2[3]));
            u32x2 wlo = {W0, W1};
            u32x2 whi = {W2, W3};
            *(u32x2*)&Pw[s_l * 20 + g * 2]     = wlo;
            *(u32x2*)&Pw[s_l * 20 + 8 + g * 2] = whi;
            // B-fragment read: P[t = g*8 .. g*8+7][s] = dwords [s*20+g*4 .. +3]
            u32x4 rv = *(const u32x4*)&Pw[s_l * 20 + g * 4];
            bf16x8 pf = __builtin_bit_cast(bf16x8, rv);
            lacc[st]    = __builtin_amdgcn_mfma_f32_16x16x32_bf16(ones, pf, lacc[st], 0, 0, 0);
            oacc[0][st] = __builtin_amdgcn_mfma_f32_16x16x32_bf16(v0, pf, oacc[0][st], 0, 0, 0);
            oacc[1][st] = __builtin_amdgcn_mfma_f32_16x16x32_bf16(v1, pf, oacc[1][st], 0, 0, 0);
        }
    }

    unsigned short* pOc = pO + (size_t)ch * PO_ELEMS;   // layout [b][n][c]
#pragma unroll
    for (int dt = 0; dt < 2; ++dt)
#pragma unroll
        for (int st = 0; st < 2; ++st) {
            int s = s0 + st * 16 + col;
            unsigned int u0 = cvtpk(oacc[dt][st][0], oacc[dt][st][1]);
            unsigned int u1 = cvtpk(oacc[dt][st][2], oacc[dt][st][3]);
            u16x4 pk = { (unsigned short)(u0 & 0xFFFF), (unsigned short)(u0 >> 16),
                         (unsigned short)(u1 & 0xFFFF), (unsigned short)(u1 >> 16) };
            *(u16x4*)&pOc[((size_t)(b * NT + s)) * 256 + h * 32 + dt * 16 + g * 4] = pk;
        }
    if (g == 0) {
#pragma unroll
        for (int st = 0; st < 2; ++st) {
            int s = s0 + st * 16 + col;
            pl[(((size_t)ch * NB + b) * NH + h) * NT + s] = lacc[st][0];
        }
    }
}

// ---------------- Combine partial chunks -> attT[b][n][c] (bf16) -------------
__global__ __launch_bounds__(256) void k_combine(const unsigned short* __restrict__ pO,
                                                 const float* __restrict__ pl,
                                                 unsigned short* __restrict__ attT) {
    int f = blockIdx.x * 256 + threadIdx.x;   // quad index, 524288 total
    int b  = f >> 18;
    int r  = f & 262143;
    int s  = r >> 6;
    int cq = (r & 63) * 4;
    int h  = cq >> 5;
    float num[4] = {0.f, 0.f, 0.f, 0.f};
    float den = 0.f;
#pragma unroll
    for (int chn = 0; chn < NCHUNK; ++chn) {
        u16x4 ov = *(const u16x4*)&pO[(size_t)chn * PO_ELEMS +
                                      ((size_t)(b * NT + s)) * 256 + cq];
        den += pl[(((size_t)chn * NB + b) * NH + h) * NT + s];
        num[0] += bf2f(ov[0]); num[1] += bf2f(ov[1]);
        num[2] += bf2f(ov[2]); num[3] += bf2f(ov[3]);
    }
    float rd = 1.0f / den;
    u16x4 res = { f2bf(num[0] * rd), f2bf(num[1] * rd),
                  f2bf(num[2] * rd), f2bf(num[3] * rd) };
    *(u16x4*)&attT[((size_t)(b * NT + s)) * 256 + cq] = res;
}

// ---------------- Output projection: bf16 MFMA + bias + residual -------------
__global__ __launch_bounds__(256) void k_out_mfma(const unsigned short* __restrict__ attT,
                                                  const unsigned short* __restrict__ wo_bf,
                                                  const float* __restrict__ bout,
                                                  const float* __restrict__ x,
                                                  float* __restrict__ out) {
    int b = blockIdx.z, o0 = blockIdx.y * 64, n0 = blockIdx.x * 64;
    int tid = threadIdx.x;
    int w = tid >> 6, lane = tid & 63, c16 = lane & 15, g = lane >> 4;
    int n_tok = n0 + w * 16 + c16;
    const unsigned short* Bsrc = attT + ((size_t)b * NT + n_tok) * 256 + g * 8;
    const unsigned short* Asrc = wo_bf + (size_t)(o0 + c16) * 256 + g * 8;
    f32x4 acc[4] = {};
    for (int kk = 0; kk < 8; ++kk) {
        bf16x8 bfr = ldbf8(Bsrc + kk * 32);
#pragma unroll
        for (int ot = 0; ot < 4; ++ot) {
            bf16x8 afr = ldbf8(Asrc + ot * 16 * 256 + kk * 32);
            acc[ot] = __builtin_amdgcn_mfma_f32_16x16x32_bf16(afr, bfr, acc[ot], 0, 0, 0);
        }
    }
#pragma unroll
    for (int ot = 0; ot < 4; ++ot) {
        int ob = o0 + ot * 16 + g * 4;
#pragma unroll
        for (int rr = 0; rr < 4; ++rr) {
            int o = ob + rr;
            size_t off = ((size_t)(b * NC + o)) * NT + n_tok;
            out[off] = acc[ot][rr] + bout[o] + x[off];
        }
    }
}

extern "C" void kernel_launch(void* const* d_in, const int* in_sizes, int n_in,
                              void* d_out, int out_size, void* d_ws, size_t ws_size,
                              hipStream_t stream) {
    const float* x    = (const float*)d_in[0];
    const float* nw   = (const float*)d_in[1];
    const float* nb   = (const float*)d_in[2];
    const float* wqkv = (const float*)d_in[3];
    const float* wout = (const float*)d_in[4];
    const float* bout = (const float*)d_in[5];
    float* out = (float*)d_out;
    char* wsb = (char*)d_ws;

    unsigned short* qkT = (unsigned short*)wsb;                        // 8 MB
    unsigned short* vbf = (unsigned short*)(wsb + 8u * 1024 * 1024);   // 4 MB
    unsigned short* pO  = (unsigned short*)(wsb + 12u * 1024 * 1024);  // 16 MB: [4ch][B][N][C] bf16
    float* pl   = (float*)(wsb + 28u * 1024 * 1024);                   // 1 MB
    float* part = (float*)(wsb + 29u * 1024 * 1024);
    float* stats = part + 1024;
    unsigned short* wo_bf = (unsigned short*)(wsb + 30u * 1024 * 1024); // 128 KB
    // xnT (4 MB) and wq_bf (384 KB) alias the pO region: both dead before
    // k_attn writes pO (stream-ordered). attT (4 MB) aliases dead qkT region.
    unsigned short* xnT   = pO;                                        // @12 MB
    unsigned short* wq_bf = (unsigned short*)(wsb + 16u * 1024 * 1024);
    unsigned short* attT = qkT;

    k_stats_partial<<<512, 256, 0, stream>>>(x, part);
    k_stats_final<<<16, 64, 0, stream>>>(part, stats);
    k_wprep<<<96, 256, 0, stream>>>(wqkv, wq_bf);
    k_wprep<<<32, 256, 0, stream>>>(wout, wo_bf);
    k_xprep<<<dim3(NT / 64, NC / 64, NB), 256, 0, stream>>>(x, nw, nb, stats, xnT);
    k_qkv_mfma<<<dim3(NT / 64, 12, NB), 256, 0, stream>>>(wq_bf, xnT, qkT, vbf);
    k_attn<<<dim3(NB * NCHUNK * NH * 32), 256, 0, stream>>>(qkT, vbf, pO, pl);
    k_combine<<<2048, 256, 0, stream>>>(pO, pl, attT);
    k_out_mfma<<<dim3(NT / 64, NC / 64, NB), 256, 0, stream>>>(attT, wo_bf, bout, x, out);
}

// Round 15
// 121.519 us; speedup vs baseline: 1.5247x; 1.0540x over previous
//
#include <hip/hip_runtime.h>

// B=2, C=256, X=Y=Z=16 -> N=4096, GROUPS=8, HEADS=8, D=32
#define NB 2
#define NC 256
#define NT 4096
#define NG 8
#define NH 8
#define EPSV 1e-5f
// (1/sqrt(32)) * log2(e): folded into Q at projection time -> softmax is exp2()
#define SCALE_L2E 0.25503164427f
#define NCHUNK 4
#define CHTOK (NT / NCHUNK)                 // 1024 tokens per chunk
#define NIT (CHTOK / 32)                    // 32 iterations per chunk
#define PO_ELEMS ((size_t)NB * NC * NT)     // bf16 elements per chunk of partial O

typedef __attribute__((ext_vector_type(8))) __bf16 bf16x8;
typedef __attribute__((ext_vector_type(8))) unsigned short u16x8;
typedef __attribute__((ext_vector_type(4))) unsigned short u16x4;
typedef __attribute__((ext_vector_type(4))) unsigned int u32x4;
typedef __attribute__((ext_vector_type(2))) unsigned int u32x2;
typedef __attribute__((ext_vector_type(4))) float f32x4;

static __device__ __forceinline__ unsigned short f2bf(float f) {
    union { float f; unsigned int u; } v; v.f = f;
    unsigned int r = v.u + 0x7fffu + ((v.u >> 16) & 1u);  // RNE
    return (unsigned short)(r >> 16);
}
static __device__ __forceinline__ float bf2f(unsigned short u) {
    union { unsigned int u; float f; } v; v.u = ((unsigned int)u) << 16;
    return v.f;
}
static __device__ __forceinline__ bf16x8 ldbf8(const unsigned short* p) {
    u16x8 u = *(const u16x8*)p;
    return __builtin_bit_cast(bf16x8, u);
}
static __device__ __forceinline__ unsigned int cvtpk(float lo, float hi) {
    unsigned int d;
    asm("v_cvt_pk_bf16_f32 %0, %1, %2" : "=v"(d) : "v"(lo), "v"(hi));
    return d;
}

// ---------------- GroupNorm statistics (two-stage, deterministic) ------------
__global__ __launch_bounds__(256) void k_stats_partial(const float* __restrict__ x,
                                                       float* __restrict__ part) {
    int bg = blockIdx.x >> 5;
    int p  = blockIdx.x & 31;
    const float4* base = (const float4*)(x + (size_t)bg * 131072 + (size_t)p * 4096);
    float s = 0.f, s2 = 0.f;
#pragma unroll
    for (int i = 0; i < 4; ++i) {
        float4 v = base[threadIdx.x + i * 256];
        s  += v.x + v.y + v.z + v.w;
        s2 += v.x * v.x + v.y * v.y + v.z * v.z + v.w * v.w;
    }
    __shared__ float ss[256], sq[256];
    ss[threadIdx.x] = s; sq[threadIdx.x] = s2;
    __syncthreads();
    for (int off = 128; off > 0; off >>= 1) {
        if (threadIdx.x < off) {
            ss[threadIdx.x] += ss[threadIdx.x + off];
            sq[threadIdx.x] += sq[threadIdx.x + off];
        }
        __syncthreads();
    }
    if (threadIdx.x == 0) {
        part[blockIdx.x * 2 + 0] = ss[0];
        part[blockIdx.x * 2 + 1] = sq[0];
    }
}

__global__ __launch_bounds__(64) void k_stats_final(const float* __restrict__ part,
                                                    float* __restrict__ stats) {
    int bg = blockIdx.x;
    float s = 0.f, s2 = 0.f;
    if (threadIdx.x < 32) {
        s  = part[(bg * 32 + threadIdx.x) * 2 + 0];
        s2 = part[(bg * 32 + threadIdx.x) * 2 + 1];
    }
#pragma unroll
    for (int off = 16; off > 0; off >>= 1) {
        s  += __shfl_down(s, off);
        s2 += __shfl_down(s2, off);
    }
    if (threadIdx.x == 0) {
        const float inv = 1.0f / 131072.0f;
        float mean = s * inv;
        float var  = s2 * inv - mean * mean;
        stats[bg * 2 + 0] = mean;
        stats[bg * 2 + 1] = rsqrtf(var + EPSV);
    }
}

// ---------------- Weight prep: both weight matrices, one launch --------------
// blocks 0..95: w_qkv (196608 floats); blocks 96..127: w_out (65536 floats)
__global__ __launch_bounds__(256) void k_wprep2(const float* __restrict__ wq,
                                                const float* __restrict__ wo,
                                                unsigned short* __restrict__ wq_bf,
                                                unsigned short* __restrict__ wo_bf) {
    int bidx = blockIdx.x;
    const float* src;
    unsigned short* dst;
    int off;
    if (bidx < 96) { src = wq; dst = wq_bf; off = bidx * 2048; }
    else           { src = wo; dst = wo_bf; off = (bidx - 96) * 2048; }
    int idx = off + threadIdx.x * 8;
    float4 a = *(const float4*)(src + idx);
    float4 c = *(const float4*)(src + idx + 4);
    u32x4 o = { cvtpk(a.x, a.y), cvtpk(a.z, a.w),
                cvtpk(c.x, c.y), cvtpk(c.z, c.w) };
    *(u32x4*)(dst + idx) = o;
}

// ---------------- x prep: GroupNorm + bf16 + transpose -> xnT[b][n][c] -------
__global__ __launch_bounds__(256) void k_xprep(const float* __restrict__ x,
                                               const float* __restrict__ nw,
                                               const float* __restrict__ nbias,
                                               const float* __restrict__ stats,
                                               unsigned short* __restrict__ xnT) {
    __shared__ unsigned short T[64][72];   // [n][c], padded
    int b = blockIdx.z, c0 = blockIdx.y * 64, n0 = blockIdx.x * 64;
    int tid = threadIdx.x;
    int c_l = tid >> 2, nq = (tid & 3) * 16;
    int c = c0 + c_l;
    int grp = c >> 5;
    float mean = stats[(b * NG + grp) * 2 + 0];
    float rstd = stats[(b * NG + grp) * 2 + 1];
    float wsc = nw[c] * rstd;
    float bb  = nbias[c] - mean * wsc;    // xn = x*wsc + bb
    const float4* src = (const float4*)(x + ((size_t)(b * NC + c)) * NT + n0 + nq);
#pragma unroll
    for (int i = 0; i < 4; ++i) {
        float4 v = src[i];
        T[nq + i * 4 + 0][c_l] = f2bf(v.x * wsc + bb);
        T[nq + i * 4 + 1][c_l] = f2bf(v.y * wsc + bb);
        T[nq + i * 4 + 2][c_l] = f2bf(v.z * wsc + bb);
        T[nq + i * 4 + 3][c_l] = f2bf(v.w * wsc + bb);
    }
    __syncthreads();
    int n_l = tid >> 2, cq = (tid & 3) * 16;
    unsigned short* dst = xnT + ((size_t)b * NT + n0 + n_l) * 256 + c0 + cq;
    *(u16x8*)dst       = *(const u16x8*)&T[n_l][cq];
    *(u16x8*)(dst + 8) = *(const u16x8*)&T[n_l][cq + 8];
}

// ---------------- QKV projection: bf16 MFMA ----------------------------------
__global__ __launch_bounds__(256) void k_qkv_mfma(const unsigned short* __restrict__ wq_bf,
                                                  const unsigned short* __restrict__ xnT,
                                                  unsigned short* __restrict__ qkT,
                                                  unsigned short* __restrict__ vbf) {
    int b = blockIdx.z, o0 = blockIdx.y * 64, n0 = blockIdx.x * 64;
    int tid = threadIdx.x;
    int w = tid >> 6, lane = tid & 63, c16 = lane & 15, g = lane >> 4;
    int n_tok = n0 + w * 16 + c16;
    const unsigned short* Bsrc = xnT + ((size_t)b * NT + n_tok) * 256 + g * 8;
    const unsigned short* Asrc = wq_bf + (size_t)(o0 + c16) * 256 + g * 8;
    f32x4 acc[4] = {};
    for (int kk = 0; kk < 8; ++kk) {
        bf16x8 bfr = ldbf8(Bsrc + kk * 32);
#pragma unroll
        for (int ot = 0; ot < 4; ++ot) {
            bf16x8 afr = ldbf8(Asrc + ot * 16 * 256 + kk * 32);
            acc[ot] = __builtin_amdgcn_mfma_f32_16x16x32_bf16(afr, bfr, acc[ot], 0, 0, 0);
        }
    }
    if (o0 < 512) {
        int qk = o0 >> 8;
        float sc = (qk == 0) ? SCALE_L2E : 1.0f;
#pragma unroll
        for (int ot = 0; ot < 4; ++ot) {
            int ob = o0 + ot * 16 + g * 4;
            int h  = (ob >> 5) & 7;
            int d4 = ob & 31;
            unsigned int u0 = cvtpk(acc[ot][0] * sc, acc[ot][1] * sc);
            unsigned int u1 = cvtpk(acc[ot][2] * sc, acc[ot][3] * sc);
            u16x4 pk = { (unsigned short)(u0 & 0xFFFF), (unsigned short)(u0 >> 16),
                         (unsigned short)(u1 & 0xFFFF), (unsigned short)(u1 >> 16) };
            *(u16x4*)(qkT + ((((size_t)qk * NB + b) * NH + h) * NT + n_tok) * 32 + d4) = pk;
        }
    } else {
#pragma unroll
        for (int ot = 0; ot < 4; ++ot) {
            int ob = (o0 - 512) + ot * 16 + g * 4;
            int h = (ob >> 5) & 7;
            int d = ob & 31;
            unsigned short* dst = vbf + (((size_t)b * NH + h) * 32 + d) * NT + n_tok;
            dst[0]      = f2bf(acc[ot][0]);
            dst[NT]     = f2bf(acc[ot][1]);
            dst[2 * NT] = f2bf(acc[ot][2]);
            dst[3 * NT] = f2bf(acc[ot][3]);
        }
    }
}

// ---------------- Attention: swapped-QK^T bf16 MFMA, split-token -------------
// (byte-identical to round-14 passing version)
__global__ __launch_bounds__(256) void k_attn(const unsigned short* __restrict__ qkT,
                                              const unsigned short* __restrict__ vbf,
                                              unsigned short* __restrict__ pO,
                                              float* __restrict__ pl) {
    __shared__ unsigned short KV[2048];   // [0,1024)=K[tok][d], [1024,2048)=V[d][tok]
    __shared__ unsigned int Pd[4][640];   // per-wave P: 32 s-rows x 20 dwords (16 used)
    int bid = blockIdx.x;
    int xcd  = bid & 7;
    int slot = bid >> 3;
    int combo = xcd * 8 + (slot >> 5);
    int sb    = slot & 31;
    int b  = combo >> 5;
    int ch = (combo >> 3) & 3;
    int h  = combo & 7;

    int tid = threadIdx.x;
    int w = tid >> 6, lane = tid & 63, col = lane & 15, g = lane >> 4;
    int s0 = sb * 128 + w * 32;

    const unsigned short* qB = qkT + ((((size_t)0 * NB + b) * NH + h) * NT) * 32;
    const unsigned short* kB = qkT + ((((size_t)1 * NB + b) * NH + h) * NT) * 32;
    const unsigned short* vB = vbf + (((size_t)b * NH + h) * 32) * NT;

    bf16x8 qf[2];
    qf[0] = ldbf8(qB + (size_t)(s0 + col) * 32 + g * 8);
    qf[1] = ldbf8(qB + (size_t)(s0 + 16 + col) * 32 + g * 8);

    u16x8 ou;
#pragma unroll
    for (int j = 0; j < 8; ++j) ou[j] = 0x3F80;  // bf16 1.0
    const bf16x8 ones = __builtin_bit_cast(bf16x8, ou);

    const unsigned short* gs;
    int gstep;
    if (tid < 128) {
        gs = kB + ((size_t)ch * CHTOK) * 32 + tid * 8;
        gstep = 1024;
    } else {
        int idx = tid - 128;
        int d = idx >> 2, tq = (idx & 3) * 8;
        gs = vB + (size_t)d * NT + ch * CHTOK + tq;
        gstep = 32;
    }

    f32x4 oacc[2][2] = {};
    f32x4 lacc[2] = {};
    unsigned int* Pw = Pd[w];

    u16x8 stg = *(const u16x8*)gs;   // prefetch iteration 0

    for (int it = 0; it < NIT; ++it) {
        __syncthreads();   // all reads of previous tile complete
        *(u16x8*)&KV[tid * 8] = stg;
        __syncthreads();   // tile fully staged
        if (it + 1 < NIT)  // issue next load early: latency hides under compute
            stg = *(const u16x8*)(gs + (size_t)(it + 1) * gstep);
        bf16x8 k0 = ldbf8(&KV[0] + col * 32 + g * 8);
        bf16x8 k1 = ldbf8(&KV[0] + (16 + col) * 32 + g * 8);
        bf16x8 v0 = ldbf8(&KV[0] + 1024 + col * 32 + g * 8);
        bf16x8 v1 = ldbf8(&KV[0] + 1024 + (16 + col) * 32 + g * 8);
        const f32x4 z = {0.f, 0.f, 0.f, 0.f};
#pragma unroll
        for (int st = 0; st < 2; ++st) {
            int s_l = st * 16 + col;
            f32x4 sa = __builtin_amdgcn_mfma_f32_16x16x32_bf16(k0, qf[st], z, 0, 0, 0);
            f32x4 sb2 = __builtin_amdgcn_mfma_f32_16x16x32_bf16(k1, qf[st], z, 0, 0, 0);
            unsigned int W0 = cvtpk(__builtin_amdgcn_exp2f(sa[0]),
                                    __builtin_amdgcn_exp2f(sa[1]));
            unsigned int W1 = cvtpk(__builtin_amdgcn_exp2f(sa[2]),
                                    __builtin_amdgcn_exp2f(sa[3]));
            unsigned int W2 = cvtpk(__builtin_amdgcn_exp2f(sb2[0]),
                                    __builtin_amdgcn_exp2f(sb2[1]));
            unsigned int W3 = cvtpk(__builtin_amdgcn_exp2f(sb2[2]),
                                    __builtin_amdgcn_exp2f(sb2[3]));
            u32x2 wlo = {W0, W1};
            u32x2 whi = {W2, W3};
            *(u32x2*)&Pw[s_l * 20 + g * 2]     = wlo;
            *(u32x2*)&Pw[s_l * 20 + 8 + g * 2] = whi;
            u32x4 rv = *(const u32x4*)&Pw[s_l * 20 + g * 4];
            bf16x8 pf = __builtin_bit_cast(bf16x8, rv);
            lacc[st]    = __builtin_amdgcn_mfma_f32_16x16x32_bf16(ones, pf, lacc[st], 0, 0, 0);
            oacc[0][st] = __builtin_amdgcn_mfma_f32_16x16x32_bf16(v0, pf, oacc[0][st], 0, 0, 0);
            oacc[1][st] = __builtin_amdgcn_mfma_f32_16x16x32_bf16(v1, pf, oacc[1][st], 0, 0, 0);
        }
    }

    unsigned short* pOc = pO + (size_t)ch * PO_ELEMS;   // layout [b][n][c]
#pragma unroll
    for (int dt = 0; dt < 2; ++dt)
#pragma unroll
        for (int st = 0; st < 2; ++st) {
            int s = s0 + st * 16 + col;
            unsigned int u0 = cvtpk(oacc[dt][st][0], oacc[dt][st][1]);
            unsigned int u1 = cvtpk(oacc[dt][st][2], oacc[dt][st][3]);
            u16x4 pk = { (unsigned short)(u0 & 0xFFFF), (unsigned short)(u0 >> 16),
                         (unsigned short)(u1 & 0xFFFF), (unsigned short)(u1 >> 16) };
            *(u16x4*)&pOc[((size_t)(b * NT + s)) * 256 + h * 32 + dt * 16 + g * 4] = pk;
        }
    if (g == 0) {
#pragma unroll
        for (int st = 0; st < 2; ++st) {
            int s = s0 + st * 16 + col;
            pl[(((size_t)ch * NB + b) * NH + h) * NT + s] = lacc[st][0];
        }
    }
}

// ---------------- Fused combine + output projection + bias + residual --------
// grid (128 n-blocks of 32 tok, NB), 512 threads = 8 waves.
// Phase 1: combine pO chunks -> LDS attL[32][264] (padded rows: 528B stride
// -> bank step 4 -> 2-way-free b128 reads in phase 2).
// Phase 2: wave w = (tg = w&1 -> 16 tokens, og = w>>2*? ) -- og = w>>1 -> 64
// outputs; MFMA projection (proven k_out_mfma pattern, B from LDS).
__global__ __launch_bounds__(512) void k_out_fused(const unsigned short* __restrict__ pO,
                                                   const float* __restrict__ pl,
                                                   const unsigned short* __restrict__ wo_bf,
                                                   const float* __restrict__ bout,
                                                   const float* __restrict__ x,
                                                   float* __restrict__ out) {
    __shared__ unsigned short attL[32 * 264];
    int b = blockIdx.y, n0 = blockIdx.x * 32;
    int tid = threadIdx.x;

    // phase 1: combine 32x256 tile (2048 quads, 4 per thread)
#pragma unroll
    for (int i = 0; i < 4; ++i) {
        int q = tid * 4 + i;
        int tok_l = q >> 6;
        int cq = (q & 63) * 4;
        int h = cq >> 5;
        int s = n0 + tok_l;
        float num[4] = {0.f, 0.f, 0.f, 0.f};
        float den = 0.f;
#pragma unroll
        for (int chn = 0; chn < NCHUNK; ++chn) {
            u16x4 ov = *(const u16x4*)&pO[(size_t)chn * PO_ELEMS +
                                          ((size_t)(b * NT + s)) * 256 + cq];
            den += pl[(((size_t)chn * NB + b) * NH + h) * NT + s];
            num[0] += bf2f(ov[0]); num[1] += bf2f(ov[1]);
            num[2] += bf2f(ov[2]); num[3] += bf2f(ov[3]);
        }
        float rd = 1.0f / den;
        u16x4 res = { f2bf(num[0] * rd), f2bf(num[1] * rd),
                      f2bf(num[2] * rd), f2bf(num[3] * rd) };
        *(u16x4*)&attL[tok_l * 264 + cq] = res;
    }
    __syncthreads();

    // phase 2: MFMA projection
    int w = tid >> 6, lane = tid & 63, c16 = lane & 15, g = lane >> 4;
    int tg = w & 1, og = w >> 1;
    int n_tok = n0 + tg * 16 + c16;
    int o0 = og * 64;
    const unsigned short* Bsrc = &attL[(tg * 16 + c16) * 264 + g * 8];
    const unsigned short* Asrc = wo_bf + (size_t)(o0 + c16) * 256 + g * 8;
    f32x4 acc[4] = {};
    for (int kk = 0; kk < 8; ++kk) {
        bf16x8 bfr = ldbf8(Bsrc + kk * 32);
#pragma unroll
        for (int ot = 0; ot < 4; ++ot) {
            bf16x8 afr = ldbf8(Asrc + ot * 16 * 256 + kk * 32);
            acc[ot] = __builtin_amdgcn_mfma_f32_16x16x32_bf16(afr, bfr, acc[ot], 0, 0, 0);
        }
    }
#pragma unroll
    for (int ot = 0; ot < 4; ++ot) {
        int ob = o0 + ot * 16 + g * 4;
#pragma unroll
        for (int rr = 0; rr < 4; ++rr) {
            int o = ob + rr;
            size_t off = ((size_t)(b * NC + o)) * NT + n_tok;
            out[off] = acc[ot][rr] + bout[o] + x[off];
        }
    }
}

extern "C" void kernel_launch(void* const* d_in, const int* in_sizes, int n_in,
                              void* d_out, int out_size, void* d_ws, size_t ws_size,
                              hipStream_t stream) {
    const float* x    = (const float*)d_in[0];
    const float* nw   = (const float*)d_in[1];
    const float* nb   = (const float*)d_in[2];
    const float* wqkv = (const float*)d_in[3];
    const float* wout = (const float*)d_in[4];
    const float* bout = (const float*)d_in[5];
    float* out = (float*)d_out;
    char* wsb = (char*)d_ws;

    unsigned short* qkT = (unsigned short*)wsb;                        // 8 MB
    unsigned short* vbf = (unsigned short*)(wsb + 8u * 1024 * 1024);   // 4 MB
    unsigned short* pO  = (unsigned short*)(wsb + 12u * 1024 * 1024);  // 16 MB: [4ch][B][N][C] bf16
    float* pl   = (float*)(wsb + 28u * 1024 * 1024);                   // 1 MB
    float* part = (float*)(wsb + 29u * 1024 * 1024);
    float* stats = part + 1024;
    unsigned short* wo_bf = (unsigned short*)(wsb + 30u * 1024 * 1024); // 128 KB
    // xnT (4 MB) and wq_bf (384 KB) alias the pO region: both dead before
    // k_attn writes pO (stream-ordered).
    unsigned short* xnT   = pO;                                        // @12 MB
    unsigned short* wq_bf = (unsigned short*)(wsb + 16u * 1024 * 1024);

    k_stats_partial<<<512, 256, 0, stream>>>(x, part);
    k_stats_final<<<16, 64, 0, stream>>>(part, stats);
    k_wprep2<<<128, 256, 0, stream>>>(wqkv, wout, wq_bf, wo_bf);
    k_xprep<<<dim3(NT / 64, NC / 64, NB), 256, 0, stream>>>(x, nw, nb, stats, xnT);
    k_qkv_mfma<<<dim3(NT / 64, 12, NB), 256, 0, stream>>>(wq_bf, xnT, qkT, vbf);
    k_attn<<<dim3(NB * NCHUNK * NH * 32), 256, 0, stream>>>(qkT, vbf, pO, pl);
    k_out_fused<<<dim3(128, NB), 512, 0, stream>>>(pO, pl, wo_bf, bout, x, out);
}

// Round 18
// 113.082 us; speedup vs baseline: 1.6385x; 1.0746x over previous
//
#include <hip/hip_runtime.h>

// B=2, C=256, X=Y=Z=16 -> N=4096, GROUPS=8, HEADS=8, D=32
#define NB 2
#define NC 256
#define NT 4096
#define NG 8
#define NH 8
#define EPSV 1e-5f
// (1/sqrt(32)) * log2(e): folded into Q at projection time -> softmax is exp2()
#define SCALE_L2E 0.25503164427f
#define NCHUNK 4
#define CHTOK (NT / NCHUNK)                 // 1024 tokens per chunk
#define NIT (CHTOK / 32)                    // 32 iterations per chunk
#define PO_ELEMS ((size_t)NB * NC * NT)     // bf16 elements per chunk of partial O

typedef __attribute__((ext_vector_type(8))) __bf16 bf16x8;
typedef __attribute__((ext_vector_type(8))) unsigned short u16x8;
typedef __attribute__((ext_vector_type(4))) unsigned short u16x4;
typedef __attribute__((ext_vector_type(4))) unsigned int u32x4;
typedef __attribute__((ext_vector_type(2))) unsigned int u32x2;
typedef __attribute__((ext_vector_type(4))) float f32x4;

static __device__ __forceinline__ unsigned short f2bf(float f) {
    union { float f; unsigned int u; } v; v.f = f;
    unsigned int r = v.u + 0x7fffu + ((v.u >> 16) & 1u);  // RNE
    return (unsigned short)(r >> 16);
}
static __device__ __forceinline__ float bf2f(unsigned short u) {
    union { unsigned int u; float f; } v; v.u = ((unsigned int)u) << 16;
    return v.f;
}
static __device__ __forceinline__ bf16x8 ldbf8(const unsigned short* p) {
    u16x8 u = *(const u16x8*)p;
    return __builtin_bit_cast(bf16x8, u);
}
static __device__ __forceinline__ unsigned int cvtpk(float lo, float hi) {
    unsigned int d;
    asm("v_cvt_pk_bf16_f32 %0, %1, %2" : "=v"(d) : "v"(lo), "v"(hi));
    return d;
}

// ---------------- GroupNorm statistics (two-stage, deterministic) ------------
__global__ __launch_bounds__(256) void k_stats_partial(const float* __restrict__ x,
                                                       float* __restrict__ part) {
    int bg = blockIdx.x >> 5;
    int p  = blockIdx.x & 31;
    const float4* base = (const float4*)(x + (size_t)bg * 131072 + (size_t)p * 4096);
    float s = 0.f, s2 = 0.f;
#pragma unroll
    for (int i = 0; i < 4; ++i) {
        float4 v = base[threadIdx.x + i * 256];
        s  += v.x + v.y + v.z + v.w;
        s2 += v.x * v.x + v.y * v.y + v.z * v.z + v.w * v.w;
    }
    __shared__ float ss[256], sq[256];
    ss[threadIdx.x] = s; sq[threadIdx.x] = s2;
    __syncthreads();
    for (int off = 128; off > 0; off >>= 1) {
        if (threadIdx.x < off) {
            ss[threadIdx.x] += ss[threadIdx.x + off];
            sq[threadIdx.x] += sq[threadIdx.x + off];
        }
        __syncthreads();
    }
    if (threadIdx.x == 0) {
        part[blockIdx.x * 2 + 0] = ss[0];
        part[blockIdx.x * 2 + 1] = sq[0];
    }
}

__global__ __launch_bounds__(64) void k_stats_final(const float* __restrict__ part,
                                                    float* __restrict__ stats) {
    int bg = blockIdx.x;
    float s = 0.f, s2 = 0.f;
    if (threadIdx.x < 32) {
        s  = part[(bg * 32 + threadIdx.x) * 2 + 0];
        s2 = part[(bg * 32 + threadIdx.x) * 2 + 1];
    }
#pragma unroll
    for (int off = 16; off > 0; off >>= 1) {
        s  += __shfl_down(s, off);
        s2 += __shfl_down(s2, off);
    }
    if (threadIdx.x == 0) {
        const float inv = 1.0f / 131072.0f;
        float mean = s * inv;
        float var  = s2 * inv - mean * mean;
        stats[bg * 2 + 0] = mean;
        stats[bg * 2 + 1] = rsqrtf(var + EPSV);
    }
}

// ---------------- Weight prep: both weight matrices, one launch --------------
__global__ __launch_bounds__(256) void k_wprep2(const float* __restrict__ wq,
                                                const float* __restrict__ wo,
                                                unsigned short* __restrict__ wq_bf,
                                                unsigned short* __restrict__ wo_bf) {
    int bidx = blockIdx.x;
    const float* src;
    unsigned short* dst;
    int off;
    if (bidx < 96) { src = wq; dst = wq_bf; off = bidx * 2048; }
    else           { src = wo; dst = wo_bf; off = (bidx - 96) * 2048; }
    int idx = off + threadIdx.x * 8;
    float4 a = *(const float4*)(src + idx);
    float4 c = *(const float4*)(src + idx + 4);
    u32x4 o = { cvtpk(a.x, a.y), cvtpk(a.z, a.w),
                cvtpk(c.x, c.y), cvtpk(c.z, c.w) };
    *(u32x4*)(dst + idx) = o;
}

// ---------------- x prep: GroupNorm + bf16 + transpose -> xnT[b][n][c] -------
__global__ __launch_bounds__(256) void k_xprep(const float* __restrict__ x,
                                               const float* __restrict__ nw,
                                               const float* __restrict__ nbias,
                                               const float* __restrict__ stats,
                                               unsigned short* __restrict__ xnT) {
    __shared__ unsigned short T[64][72];   // [n][c], padded
    int b = blockIdx.z, c0 = blockIdx.y * 64, n0 = blockIdx.x * 64;
    int tid = threadIdx.x;
    int c_l = tid >> 2, nq = (tid & 3) * 16;
    int c = c0 + c_l;
    int grp = c >> 5;
    float mean = stats[(b * NG + grp) * 2 + 0];
    float rstd = stats[(b * NG + grp) * 2 + 1];
    float wsc = nw[c] * rstd;
    float bb  = nbias[c] - mean * wsc;    // xn = x*wsc + bb
    const float4* src = (const float4*)(x + ((size_t)(b * NC + c)) * NT + n0 + nq);
#pragma unroll
    for (int i = 0; i < 4; ++i) {
        float4 v = src[i];
        T[nq + i * 4 + 0][c_l] = f2bf(v.x * wsc + bb);
        T[nq + i * 4 + 1][c_l] = f2bf(v.y * wsc + bb);
        T[nq + i * 4 + 2][c_l] = f2bf(v.z * wsc + bb);
        T[nq + i * 4 + 3][c_l] = f2bf(v.w * wsc + bb);
    }
    __syncthreads();
    int n_l = tid >> 2, cq = (tid & 3) * 16;
    unsigned short* dst = xnT + ((size_t)b * NT + n0 + n_l) * 256 + c0 + cq;
    *(u16x8*)dst       = *(const u16x8*)&T[n_l][cq];
    *(u16x8*)(dst + 8) = *(const u16x8*)&T[n_l][cq + 8];
}

// ---------------- QKV projection: bf16 MFMA ----------------------------------
__global__ __launch_bounds__(256) void k_qkv_mfma(const unsigned short* __restrict__ wq_bf,
                                                  const unsigned short* __restrict__ xnT,
                                                  unsigned short* __restrict__ qkT,
                                                  unsigned short* __restrict__ vbf) {
    int b = blockIdx.z, o0 = blockIdx.y * 64, n0 = blockIdx.x * 64;
    int tid = threadIdx.x;
    int w = tid >> 6, lane = tid & 63, c16 = lane & 15, g = lane >> 4;
    int n_tok = n0 + w * 16 + c16;
    const unsigned short* Bsrc = xnT + ((size_t)b * NT + n_tok) * 256 + g * 8;
    const unsigned short* Asrc = wq_bf + (size_t)(o0 + c16) * 256 + g * 8;
    f32x4 acc[4] = {};
    for (int kk = 0; kk < 8; ++kk) {
        bf16x8 bfr = ldbf8(Bsrc + kk * 32);
#pragma unroll
        for (int ot = 0; ot < 4; ++ot) {
            bf16x8 afr = ldbf8(Asrc + ot * 16 * 256 + kk * 32);
            acc[ot] = __builtin_amdgcn_mfma_f32_16x16x32_bf16(afr, bfr, acc[ot], 0, 0, 0);
        }
    }
    if (o0 < 512) {
        int qk = o0 >> 8;
        float sc = (qk == 0) ? SCALE_L2E : 1.0f;
#pragma unroll
        for (int ot = 0; ot < 4; ++ot) {
            int ob = o0 + ot * 16 + g * 4;
            int h  = (ob >> 5) & 7;
            int d4 = ob & 31;
            unsigned int u0 = cvtpk(acc[ot][0] * sc, acc[ot][1] * sc);
            unsigned int u1 = cvtpk(acc[ot][2] * sc, acc[ot][3] * sc);
            u16x4 pk = { (unsigned short)(u0 & 0xFFFF), (unsigned short)(u0 >> 16),
                         (unsigned short)(u1 & 0xFFFF), (unsigned short)(u1 >> 16) };
            *(u16x4*)(qkT + ((((size_t)qk * NB + b) * NH + h) * NT + n_tok) * 32 + d4) = pk;
        }
    } else {
#pragma unroll
        for (int ot = 0; ot < 4; ++ot) {
            int ob = (o0 - 512) + ot * 16 + g * 4;
            int h = (ob >> 5) & 7;
            int d = ob & 31;
            unsigned short* dst = vbf + (((size_t)b * NH + h) * 32 + d) * NT + n_tok;
            dst[0]      = f2bf(acc[ot][0]);
            dst[NT]     = f2bf(acc[ot][1]);
            dst[2 * NT] = f2bf(acc[ot][2]);
            dst[3 * NT] = f2bf(acc[ot][3]);
        }
    }
}

// ---------------- Attention: swapped-QK^T bf16 MFMA, split-token -------------
// V staged with PERMUTED token order so the QK^T C/D fragment IS the PV
// B-fragment in-register (slot 8g+j <-> token {4g+j | j<4 ; 16+4g+j-4}).
// K/V LDS rows padded to 40 shorts (80B, bank step 20) -> worst 2-way (free).
// STAGING REVERTED to the conservative round-13 schedule (barrier; load+store;
// barrier; compute) — round-17's prefetch-early variant showed a rare
// post-timing race; this schedule has two clean post-timing runs (r8, r13).
__global__ __launch_bounds__(256) void k_attn(const unsigned short* __restrict__ qkT,
                                              const unsigned short* __restrict__ vbf,
                                              unsigned short* __restrict__ pO,
                                              float* __restrict__ pl) {
    __shared__ unsigned short KV[2560];   // K: [32 tok][40]; V: 1280 + [32 d][40 slots]
    int bid = blockIdx.x;
    int xcd  = bid & 7;
    int slot = bid >> 3;
    int combo = xcd * 8 + (slot >> 5);
    int sb    = slot & 31;
    int b  = combo >> 5;
    int ch = (combo >> 3) & 3;
    int h  = combo & 7;

    int tid = threadIdx.x;
    int w = tid >> 6, lane = tid & 63, col = lane & 15, g = lane >> 4;
    int s0 = sb * 128 + w * 32;

    const unsigned short* qB = qkT + ((((size_t)0 * NB + b) * NH + h) * NT) * 32;
    const unsigned short* kB = qkT + ((((size_t)1 * NB + b) * NH + h) * NT) * 32;
    const unsigned short* vB = vbf + (((size_t)b * NH + h) * 32) * NT;

    bf16x8 qf[2];
    qf[0] = ldbf8(qB + (size_t)(s0 + col) * 32 + g * 8);
    qf[1] = ldbf8(qB + (size_t)(s0 + 16 + col) * 32 + g * 8);

    u16x8 ou;
#pragma unroll
    for (int j = 0; j < 8; ++j) ou[j] = 0x3F80;  // bf16 1.0
    const bf16x8 ones = __builtin_bit_cast(bf16x8, ou);

    // staging: tid<128 -> K tile ([tok][d], 16B/thread);
    // tid>=128 -> V tile rows with slot permutation (2x 8B loads, 1x 16B write)
    const unsigned short* gsK = kB;
    const unsigned short* gsVA = vB;
    const unsigned short* gsVB = vB;
    int ldst = 0;
    if (tid < 128) {
        gsK  = kB + ((size_t)ch * CHTOK) * 32 + tid * 8;
        ldst = (tid >> 2) * 40 + (tid & 3) * 8;
    } else {
        int idx = tid - 128;
        int d = idx >> 2, q = idx & 3;
        gsVA = vB + (size_t)d * NT + ch * CHTOK + q * 4;        // tokens 4q..4q+3
        gsVB = gsVA + 16;                                       // tokens 16+4q..+3
        ldst = 1280 + d * 40 + q * 8;
    }

    f32x4 oacc[2][2] = {};
    f32x4 lacc[2] = {};

    for (int it = 0; it < NIT; ++it) {
        __syncthreads();   // all reads of previous tile complete
        if (tid < 128) {
            *(u16x8*)&KV[ldst] = *(const u16x8*)(gsK + (size_t)it * 1024);
        } else {
            u16x4 va4 = *(const u16x4*)(gsVA + it * 32);
            u16x4 vb4 = *(const u16x4*)(gsVB + it * 32);
            u16x8 vv = { va4[0], va4[1], va4[2], va4[3],
                         vb4[0], vb4[1], vb4[2], vb4[3] };
            *(u16x8*)&KV[ldst] = vv;
        }
        __syncthreads();   // tile fully staged
        bf16x8 k0 = ldbf8(&KV[col * 40 + g * 8]);
        bf16x8 k1 = ldbf8(&KV[(16 + col) * 40 + g * 8]);
        bf16x8 v0 = ldbf8(&KV[1280 + col * 40 + g * 8]);
        bf16x8 v1 = ldbf8(&KV[1280 + (16 + col) * 40 + g * 8]);
        const f32x4 z = {0.f, 0.f, 0.f, 0.f};
#pragma unroll
        for (int st = 0; st < 2; ++st) {
            f32x4 sa = __builtin_amdgcn_mfma_f32_16x16x32_bf16(k0, qf[st], z, 0, 0, 0);
            f32x4 sb2 = __builtin_amdgcn_mfma_f32_16x16x32_bf16(k1, qf[st], z, 0, 0, 0);
            // no-max softmax (logits bounded): P = exp2(S)
            // lane holds P for tokens {4g..4g+3} (sa) and {16+4g..+3} (sb2)
            // = exactly the B-fragment slots 8g..8g+7 under the V permutation.
            unsigned int W0 = cvtpk(__builtin_amdgcn_exp2f(sa[0]),
                                    __builtin_amdgcn_exp2f(sa[1]));
            unsigned int W1 = cvtpk(__builtin_amdgcn_exp2f(sa[2]),
                                    __builtin_amdgcn_exp2f(sa[3]));
            unsigned int W2 = cvtpk(__builtin_amdgcn_exp2f(sb2[0]),
                                    __builtin_amdgcn_exp2f(sb2[1]));
            unsigned int W3 = cvtpk(__builtin_amdgcn_exp2f(sb2[2]),
                                    __builtin_amdgcn_exp2f(sb2[3]));
            u32x4 pbw = {W0, W1, W2, W3};
            bf16x8 pf = __builtin_bit_cast(bf16x8, pbw);
            lacc[st]    = __builtin_amdgcn_mfma_f32_16x16x32_bf16(ones, pf, lacc[st], 0, 0, 0);
            oacc[0][st] = __builtin_amdgcn_mfma_f32_16x16x32_bf16(v0, pf, oacc[0][st], 0, 0, 0);
            oacc[1][st] = __builtin_amdgcn_mfma_f32_16x16x32_bf16(v1, pf, oacc[1][st], 0, 0, 0);
        }
    }

    unsigned short* pOc = pO + (size_t)ch * PO_ELEMS;   // layout [b][n][c]
#pragma unroll
    for (int dt = 0; dt < 2; ++dt)
#pragma unroll
        for (int st = 0; st < 2; ++st) {
            int s = s0 + st * 16 + col;
            unsigned int u0 = cvtpk(oacc[dt][st][0], oacc[dt][st][1]);
            unsigned int u1 = cvtpk(oacc[dt][st][2], oacc[dt][st][3]);
            u16x4 pk = { (unsigned short)(u0 & 0xFFFF), (unsigned short)(u0 >> 16),
                         (unsigned short)(u1 & 0xFFFF), (unsigned short)(u1 >> 16) };
            *(u16x4*)&pOc[((size_t)(b * NT + s)) * 256 + h * 32 + dt * 16 + g * 4] = pk;
        }
    if (g == 0) {
#pragma unroll
        for (int st = 0; st < 2; ++st) {
            int s = s0 + st * 16 + col;
            pl[(((size_t)ch * NB + b) * NH + h) * NT + s] = lacc[st][0];
        }
    }
}

// ---------------- Fused combine + output projection + bias + residual --------
__global__ __launch_bounds__(512) void k_out_fused(const unsigned short* __restrict__ pO,
                                                   const float* __restrict__ pl,
                                                   const unsigned short* __restrict__ wo_bf,
                                                   const float* __restrict__ bout,
                                                   const float* __restrict__ x,
                                                   float* __restrict__ out) {
    __shared__ unsigned short attL[32 * 264];
    int b = blockIdx.y, n0 = blockIdx.x * 32;
    int tid = threadIdx.x;

    // phase 1: combine 32x256 tile (2048 quads, 4 per thread)
#pragma unroll
    for (int i = 0; i < 4; ++i) {
        int q = tid * 4 + i;
        int tok_l = q >> 6;
        int cq = (q & 63) * 4;
        int h = cq >> 5;
        int s = n0 + tok_l;
        float num[4] = {0.f, 0.f, 0.f, 0.f};
        float den = 0.f;
#pragma unroll
        for (int chn = 0; chn < NCHUNK; ++chn) {
            u16x4 ov = *(const u16x4*)&pO[(size_t)chn * PO_ELEMS +
                                          ((size_t)(b * NT + s)) * 256 + cq];
            den += pl[(((size_t)chn * NB + b) * NH + h) * NT + s];
            num[0] += bf2f(ov[0]); num[1] += bf2f(ov[1]);
            num[2] += bf2f(ov[2]); num[3] += bf2f(ov[3]);
        }
        float rd = 1.0f / den;
        u16x4 res = { f2bf(num[0] * rd), f2bf(num[1] * rd),
                      f2bf(num[2] * rd), f2bf(num[3] * rd) };
        *(u16x4*)&attL[tok_l * 264 + cq] = res;
    }
    __syncthreads();

    // phase 2: MFMA projection
    int w = tid >> 6, lane = tid & 63, c16 = lane & 15, g = lane >> 4;
    int tg = w & 1, og = w >> 1;
    int n_tok = n0 + tg * 16 + c16;
    int o0 = og * 64;
    const unsigned short* Bsrc = &attL[(tg * 16 + c16) * 264 + g * 8];
    const unsigned short* Asrc = wo_bf + (size_t)(o0 + c16) * 256 + g * 8;
    f32x4 acc[4] = {};
    for (int kk = 0; kk < 8; ++kk) {
        bf16x8 bfr = ldbf8(Bsrc + kk * 32);
#pragma unroll
        for (int ot = 0; ot < 4; ++ot) {
            bf16x8 afr = ldbf8(Asrc + ot * 16 * 256 + kk * 32);
            acc[ot] = __builtin_amdgcn_mfma_f32_16x16x32_bf16(afr, bfr, acc[ot], 0, 0, 0);
        }
    }
#pragma unroll
    for (int ot = 0; ot < 4; ++ot) {
        int ob = o0 + ot * 16 + g * 4;
#pragma unroll
        for (int rr = 0; rr < 4; ++rr) {
            int o = ob + rr;
            size_t off = ((size_t)(b * NC + o)) * NT + n_tok;
            out[off] = acc[ot][rr] + bout[o] + x[off];
        }
    }
}

extern "C" void kernel_launch(void* const* d_in, const int* in_sizes, int n_in,
                              void* d_out, int out_size, void* d_ws, size_t ws_size,
                              hipStream_t stream) {
    const float* x    = (const float*)d_in[0];
    const float* nw   = (const float*)d_in[1];
    const float* nb   = (const float*)d_in[2];
    const float* wqkv = (const float*)d_in[3];
    const float* wout = (const float*)d_in[4];
    const float* bout = (const float*)d_in[5];
    float* out = (float*)d_out;
    char* wsb = (char*)d_ws;

    unsigned short* qkT = (unsigned short*)wsb;                        // 8 MB
    unsigned short* vbf = (unsigned short*)(wsb + 8u * 1024 * 1024);   // 4 MB
    unsigned short* pO  = (unsigned short*)(wsb + 12u * 1024 * 1024);  // 16 MB: [4ch][B][N][C] bf16
    float* pl   = (float*)(wsb + 28u * 1024 * 1024);                   // 1 MB
    float* part = (float*)(wsb + 29u * 1024 * 1024);
    float* stats = part + 1024;
    unsigned short* wo_bf = (unsigned short*)(wsb + 30u * 1024 * 1024); // 128 KB
    // xnT (4 MB) and wq_bf (384 KB) alias the pO region: both dead before
    // k_attn writes pO (stream-ordered).
    unsigned short* xnT   = pO;                                        // @12 MB
    unsigned short* wq_bf = (unsigned short*)(wsb + 16u * 1024 * 1024);

    k_stats_partial<<<512, 256, 0, stream>>>(x, part);
    k_stats_final<<<16, 64, 0, stream>>>(part, stats);
    k_wprep2<<<128, 256, 0, stream>>>(wqkv, wout, wq_bf, wo_bf);
    k_xprep<<<dim3(NT / 64, NC / 64, NB), 256, 0, stream>>>(x, nw, nb, stats, xnT);
    k_qkv_mfma<<<dim3(NT / 64, 12, NB), 256, 0, stream>>>(wq_bf, xnT, qkT, vbf);
    k_attn<<<dim3(NB * NCHUNK * NH * 32), 256, 0, stream>>>(qkT, vbf, pO, pl);
    k_out_fused<<<dim3(128, NB), 512, 0, stream>>>(pO, pl, wo_bf, bout, x, out);
}